// Round 24
// baseline (611.426 us; speedup 1.0000x reference)
//
#include <hip/hip_runtime.h>
#include <math.h>

// ---- model dims ----
#define DIN_   1024
#define DSTATE_ 64
#define NH_    32
#define HDIM_  32
#define CONVD_ 1152   // DIN + 2*DSTATE
#define DPROJ_ 2208   // 2*DIN + 2*DSTATE + NH
#define HID_   512
#define LSEQ_  4096
#define BB_    2
#define LT_    2048   // after stride-2 downsample
#define NHEAD_ 8
#define HD_    64     // head dim = 512/8
#define DFF_   1024
#define LC_    256    // scan chunk length
#define NC_    16     // number of chunks (LSEQ_/LC_)
#define NS_    8      // attention KV splits
#define KTS_   (LT_ / 64 / NS_)   // 4 K-tiles per split

typedef __attribute__((ext_vector_type(8))) short bf16x8;
typedef __attribute__((ext_vector_type(4))) short s16x4;
typedef __attribute__((ext_vector_type(4))) float f32x4;

__device__ __forceinline__ float siluf(float x) { return x / (1.f + __expf(-x)); }

__device__ __forceinline__ short f2b(float f) {
  union { float f; unsigned u; } v; v.f = f;
  unsigned r = (v.u + 0x7fffu + ((v.u >> 16) & 1u)) >> 16;
  return (short)r;
}

// truncation bf16 (1 op) — for internal P matrices only
__device__ __forceinline__ short f2bt(float f) {
  union { float f; unsigned u; } v; v.f = f;
  return (short)(v.u >> 16);
}

__device__ __forceinline__ float b2f(short s) {
  union { unsigned u; float f; } v; v.u = ((unsigned)(unsigned short)s) << 16;
  return v.f;
}

// async global->LDS 16B per lane; lds base must be wave-uniform
__device__ __forceinline__ void gload16(const short* g, short* lds_base) {
#if __has_builtin(__builtin_amdgcn_global_load_lds)
  __builtin_amdgcn_global_load_lds((const __attribute__((address_space(1))) void*)g,
                                   (__attribute__((address_space(3))) void*)lds_base, 16, 0, 0);
#else
  int l = threadIdx.x & 63;
  ((bf16x8*)lds_base)[l] = *(const bf16x8*)g;
#endif
}

// XCD-aware bijective block-id swizzle (m204 form)
__device__ __forceinline__ void xcd_swz(int& bx, int& by, int& bz) {
  int nbx = gridDim.x, nby = gridDim.y;
  int nwg = nbx * nby * gridDim.z;
  int orig = (blockIdx.z * nby + blockIdx.y) * nbx + blockIdx.x;
  int q = nwg >> 3, r = nwg & 7;
  int xcd = orig & 7, lin = orig >> 3;
  int wg = (xcd < r ? xcd * (q + 1) : r * (q + 1) + (xcd - r) * q) + lin;
  bx = wg % nbx; wg /= nbx;
  by = wg % nby;
  bz = wg / nby;
}

// ============================================================
// fp32 -> bf16 elementwise (8 per thread)
// ============================================================
__global__ void ec_f2b(const float* __restrict__ in, short* __restrict__ out, int n8)
{
  int i = blockIdx.x * 256 + threadIdx.x;
  if (i >= n8) return;
  const float4* p = (const float4*)(in + (size_t)i * 8);
  float4 a = p[0], b = p[1];
  bf16x8 o;
  o[0] = f2b(a.x); o[1] = f2b(a.y); o[2] = f2b(a.z); o[3] = f2b(a.w);
  o[4] = f2b(b.x); o[5] = f2b(b.y); o[6] = f2b(b.z); o[7] = f2b(b.w);
  *(bf16x8*)(out + (size_t)i * 8) = o;
}

// ============================================================
// weight convert+transpose: W fp32 [K,N] -> Wt bf16 [N,K]
// ============================================================
__global__ __launch_bounds__(256) void ec_w2bt(const float* __restrict__ W,
                                               short* __restrict__ Wt, int K, int N)
{
  __shared__ float t[32][33];
  int k0 = blockIdx.x * 32, n0 = blockIdx.y * 32;
  int tx = threadIdx.x & 31, ty = threadIdx.x >> 5;
#pragma unroll
  for (int i = 0; i < 32; i += 8) t[ty + i][tx] = W[(size_t)(k0 + ty + i) * N + n0 + tx];
  __syncthreads();
#pragma unroll
  for (int i = 0; i < 32; i += 8) Wt[(size_t)(n0 + ty + i) * K + k0 + tx] = f2b(t[tx][ty + i]);
}

// ============================================================
// ds_w (O,I,K=3) -> Wt bf16 [O, K*512] with layout Wt[o][k*512+i]
// ============================================================
__global__ void ec_dswt(const float* __restrict__ w, short* __restrict__ wt)
{
  int idx = blockIdx.x * 256 + threadIdx.x;
  if (idx >= HID_ * 1536) return;
  int o = idx / 1536, r = idx % 1536;
  int k = r >> 9, i = r & 511;
  wt[idx] = f2b(w[((size_t)o * HID_ + i) * 3 + k]);
}

// ============================================================
// conv weight transpose: cw [CONVD_][4] -> cwt [4][CONVD_]
// ============================================================
__global__ void ec_cwt(const float* __restrict__ cw, float* __restrict__ cwt)
{
  int idx = blockIdx.x * 256 + threadIdx.x;
  if (idx >= CONVD_ * 4) return;
  int j = idx / CONVD_, c = idx % CONVD_;
  cwt[idx] = cw[c * 4 + j];
}

// ============================================================
// bf16 MFMA GEMM, 64x64 tile, BK=64, XCD-swizzled, slot-swizzled LDS
// act: 0=none, 1=gelu(exact), 2=scale cols<HID_ by 0.125 (attn q pre-scale)
// ============================================================
__global__ __launch_bounds__(256) void ec_gemm16b(
    const short* __restrict__ A, const short* __restrict__ Wt,
    const float* __restrict__ bias, const float* __restrict__ res,
    float* __restrict__ Cf, short* __restrict__ Ch,
    int M, int N, int K, int act, int lda, long Az, int Mz)
{
  __shared__ short As_[2][4096];   // [64 rows][64 k] bf16, slot-swizzled
  __shared__ short Bs_[2][4096];
  int bxi, byi, bzi;
  xcd_swz(bxi, byi, bzi);
  A += (size_t)bzi * Az;
  const int mz = bzi * Mz;
  const int tid = threadIdx.x;
  const int l = tid & 63, w = tid >> 6;
  const int m0 = byi * 64, n0 = bxi * 64;
  const int wm = (w >> 1) * 32, wn = (w & 1) * 32;
  const int lr = l & 15, lk = l >> 4;
  const int srow = w * 8 + (l >> 3);
  const int scol = ((l & 7) ^ (l >> 3)) * 8;
  const int rs0 = ((0 * 4 + lk) ^ (lr & 7)) * 8;
  const int rs1 = ((1 * 4 + lk) ^ (lr & 7)) * 8;

  f32x4 acc[2][2];
#pragma unroll
  for (int i = 0; i < 2; ++i)
#pragma unroll
    for (int j = 0; j < 2; ++j) acc[i][j] = f32x4{0.f, 0.f, 0.f, 0.f};

#pragma unroll
  for (int q = 0; q < 2; ++q) {
    int r = q * 32 + srow;
    const short* ga = A + (size_t)(m0 + r) * lda + scol;
    int rb = n0 + r; if (rb > N - 1) rb = N - 1;
    const short* gb = Wt + (size_t)rb * K + scol;
    gload16(ga, &As_[0][(q * 32 + w * 8) * 64]);
    gload16(gb, &Bs_[0][(q * 32 + w * 8) * 64]);
  }

  const int KT = K >> 6;
  for (int kt = 0; kt < KT; ++kt) {
    __syncthreads();
    if (kt + 1 < KT) {
      int k0 = (kt + 1) << 6;
      int nb = (kt + 1) & 1;
#pragma unroll
      for (int q = 0; q < 2; ++q) {
        int r = q * 32 + srow;
        const short* ga = A + (size_t)(m0 + r) * lda + k0 + scol;
        int rb = n0 + r; if (rb > N - 1) rb = N - 1;
        const short* gb = Wt + (size_t)rb * K + k0 + scol;
        gload16(ga, &As_[nb][(q * 32 + w * 8) * 64]);
        gload16(gb, &Bs_[nb][(q * 32 + w * 8) * 64]);
      }
    }
    int cb = kt & 1;
#pragma unroll
    for (int ksub = 0; ksub < 2; ++ksub) {
      const int rs = ksub ? rs1 : rs0;
      bf16x8 af[2], bfv[2];
#pragma unroll
      for (int mf = 0; mf < 2; ++mf)
        af[mf] = *(const bf16x8*)&As_[cb][(wm + mf * 16 + lr) * 64 + rs];
#pragma unroll
      for (int nf = 0; nf < 2; ++nf)
        bfv[nf] = *(const bf16x8*)&Bs_[cb][(wn + nf * 16 + lr) * 64 + rs];
#pragma unroll
      for (int mf = 0; mf < 2; ++mf)
#pragma unroll
        for (int nf = 0; nf < 2; ++nf)
          acc[mf][nf] = __builtin_amdgcn_mfma_f32_16x16x32_bf16(af[mf], bfv[nf], acc[mf][nf], 0, 0, 0);
    }
  }

#pragma unroll
  for (int mf = 0; mf < 2; ++mf)
#pragma unroll
    for (int nf = 0; nf < 2; ++nf)
#pragma unroll
      for (int r = 0; r < 4; ++r) {
        int m = mz + m0 + wm + mf * 16 + lk * 4 + r;
        int n = n0 + wn + nf * 16 + lr;
        if (n < N) {
          float v = acc[mf][nf][r];
          if (bias) v += bias[n];
          if (act == 1) v = 0.5f * v * (1.f + erff(v * 0.70710678118f));
          else if (act == 2 && n < HID_) v *= 0.125f;
          if (res) v += res[(size_t)m * N + n];
          if (Cf) Cf[(size_t)m * N + n] = v;
          if (Ch) Ch[(size_t)m * N + n] = f2b(v);
        }
      }
}

static inline void gemm16b(hipStream_t s, const short* A, const short* Wt, const float* bias,
                           const float* res, float* Cf, short* Ch, int M, int N, int K, int act) {
  dim3 g((N + 63) / 64, M / 64), b(256);
  ec_gemm16b<<<g, b, 0, s>>>(A, Wt, bias, res, Cf, Ch, M, N, K, act, K, 0, 0);
}

// ============================================================
// bf16 MFMA GEMM, 64x128 tile, BK=64: 16 MFMA / 12 ds_read per wave
// per barrier (2x the 64x64 kernel's MFMA:barrier ratio). LDS 48KB
// (3 blocks/CU). Same slot-swizzle involution (rule #21).
// act: 0=none, 1=gelu, 2=q-scale 0.125 + Cv tile-major V^T write.
// grid ((N+127)/128, M/64). lda == K.
// ============================================================
__global__ __launch_bounds__(256) void ec_gemm16bw(
    const short* __restrict__ A, const short* __restrict__ Wt,
    const float* __restrict__ bias, short* __restrict__ Ch, short* __restrict__ Cv,
    int M, int N, int K, int act)
{
  __shared__ short As_[2][4096];   // [64 rows][64 k]
  __shared__ short Bs_[2][8192];   // [128 rows][64 k]
  int bxi, byi, bzi;
  xcd_swz(bxi, byi, bzi);
  const int tid = threadIdx.x;
  const int l = tid & 63, w = tid >> 6;
  const int m0 = byi * 64, n0 = bxi * 128;
  const int wm = (w >> 1) * 32, wn = (w & 1) * 64;
  const int lr = l & 15, lk = l >> 4;
  const int srow = w * 8 + (l >> 3);
  const int scol = ((l & 7) ^ (l >> 3)) * 8;
  const int rs0 = ((0 * 4 + lk) ^ (lr & 7)) * 8;
  const int rs1 = ((1 * 4 + lk) ^ (lr & 7)) * 8;

  f32x4 acc[2][4];
#pragma unroll
  for (int i = 0; i < 2; ++i)
#pragma unroll
    for (int j = 0; j < 4; ++j) acc[i][j] = f32x4{0.f, 0.f, 0.f, 0.f};

#pragma unroll
  for (int q = 0; q < 2; ++q) {
    int r = q * 32 + srow;
    gload16(A + (size_t)(m0 + r) * K + scol, &As_[0][(q * 32 + w * 8) * 64]);
  }
#pragma unroll
  for (int q = 0; q < 4; ++q) {
    int r = q * 32 + srow;
    int rb = n0 + r; if (rb > N - 1) rb = N - 1;
    gload16(Wt + (size_t)rb * K + scol, &Bs_[0][(q * 32 + w * 8) * 64]);
  }

  const int KT = K >> 6;
  for (int kt = 0; kt < KT; ++kt) {
    __syncthreads();
    if (kt + 1 < KT) {
      int k0 = (kt + 1) << 6;
      int nb = (kt + 1) & 1;
#pragma unroll
      for (int q = 0; q < 2; ++q) {
        int r = q * 32 + srow;
        gload16(A + (size_t)(m0 + r) * K + k0 + scol, &As_[nb][(q * 32 + w * 8) * 64]);
      }
#pragma unroll
      for (int q = 0; q < 4; ++q) {
        int r = q * 32 + srow;
        int rb = n0 + r; if (rb > N - 1) rb = N - 1;
        gload16(Wt + (size_t)rb * K + k0 + scol, &Bs_[nb][(q * 32 + w * 8) * 64]);
      }
    }
    int cb = kt & 1;
#pragma unroll
    for (int ksub = 0; ksub < 2; ++ksub) {
      const int rs = ksub ? rs1 : rs0;
      bf16x8 af[2], bfv[4];
#pragma unroll
      for (int mf = 0; mf < 2; ++mf)
        af[mf] = *(const bf16x8*)&As_[cb][(wm + mf * 16 + lr) * 64 + rs];
#pragma unroll
      for (int nf = 0; nf < 4; ++nf)
        bfv[nf] = *(const bf16x8*)&Bs_[cb][(wn + nf * 16 + lr) * 64 + rs];
#pragma unroll
      for (int mf = 0; mf < 2; ++mf)
#pragma unroll
        for (int nf = 0; nf < 4; ++nf)
          acc[mf][nf] = __builtin_amdgcn_mfma_f32_16x16x32_bf16(af[mf], bfv[nf], acc[mf][nf], 0, 0, 0);
    }
  }

  if (Cv && act == 2 && n0 >= 2 * HID_) {
    // V slice of qkv: write tile-major transposed V^T for the attention kernel
#pragma unroll
    for (int mf = 0; mf < 2; ++mf) {
      int mrow = m0 + wm + mf * 16 + lk * 4;
      int bb = mrow >> 11, tt = mrow & (LT_ - 1);
#pragma unroll
      for (int nf = 0; nf < 4; ++nf) {
        int n = n0 + wn + nf * 16 + lr;
        int vcol = n - 2 * HID_;
        int hh = vcol >> 6, d = vcol & 63;
        size_t tb = (((size_t)(bb * NHEAD_ + hh) * (LT_ / 64) + (tt >> 6)) << 12) + (tt & 63);
        float bv = bias ? bias[n] : 0.f;
        s16x4 ov;
#pragma unroll
        for (int r = 0; r < 4; ++r) ov[r] = f2b(acc[mf][nf][r] + bv);
        *(s16x4*)&Cv[tb + (size_t)d * 64] = ov;
      }
    }
    return;
  }

#pragma unroll
  for (int mf = 0; mf < 2; ++mf)
#pragma unroll
    for (int nf = 0; nf < 4; ++nf)
#pragma unroll
      for (int r = 0; r < 4; ++r) {
        int m = m0 + wm + mf * 16 + lk * 4 + r;
        int n = n0 + wn + nf * 16 + lr;
        if (n < N) {
          float v = acc[mf][nf][r];
          if (bias) v += bias[n];
          if (act == 1) v = 0.5f * v * (1.f + erff(v * 0.70710678118f));
          else if (act == 2 && n < HID_) v *= 0.125f;
          Ch[(size_t)m * N + n] = f2b(v);
        }
      }
}

// fixup for dsconv GEMM boundary rows (lo=0 per batch), 4-wide
__global__ __launch_bounds__(512) void ec_dsfix(
    const short* __restrict__ x16, const short* __restrict__ wt,
    const float* __restrict__ bias, float* __restrict__ dsf, short* __restrict__ ds16)
{
  const int b = blockIdx.x, o = threadIdx.x;
  float v = bias[o];
#pragma unroll
  for (int k = 1; k < 3; ++k) {
    const short* xr = x16 + ((size_t)b * LSEQ_ + (k - 1)) * HID_;
    const short* wr = wt + (size_t)o * 1536 + k * 512;
    for (int i = 0; i < 512; i += 4) {
      s16x4 xv = *(const s16x4*)(xr + i);
      s16x4 wv = *(const s16x4*)(wr + i);
      v += b2f(xv[0]) * b2f(wv[0]) + b2f(xv[1]) * b2f(wv[1])
         + b2f(xv[2]) * b2f(wv[2]) + b2f(xv[3]) * b2f(wv[3]);
    }
  }
  dsf[(size_t)b * LT_ * HID_ + o] = v;
  ds16[(size_t)b * LT_ * HID_ + o] = f2b(v);
}

// ============================================================
// Fused depthwise causal conv (DCONV=4) + SiLU, bf16 in/out
// ============================================================
__global__ __launch_bounds__(256) void ec_conv1d_silu(
    const short* __restrict__ zx16, const float* __restrict__ cwt,
    const float* __restrict__ cb, short* __restrict__ xbc16,
    short* __restrict__ B16, short* __restrict__ C16)
{
  int idx = blockIdx.x * 256 + threadIdx.x;
  const int NG = CONVD_ / 4;  // 288 channel groups
  if (idx >= BB_ * LSEQ_ * NG) return;
  int cg = idx % NG;
  int row = idx / NG;
  int l = row & (LSEQ_ - 1);
  int c0 = cg * 4;
  float4 cbv = *(const float4*)(cb + c0);
  float a0 = cbv.x, a1 = cbv.y, a2 = cbv.z, a3 = cbv.w;
#pragma unroll
  for (int j = 0; j < 4; ++j) {
    int ll = l - 3 + j;
    if (ll >= 0) {
      s16x4 xv = *(const s16x4*)(zx16 + (size_t)(row + ll - l) * DPROJ_ + DIN_ + c0);
      float4 wv = *(const float4*)(cwt + j * CONVD_ + c0);
      a0 += b2f(xv[0]) * wv.x;
      a1 += b2f(xv[1]) * wv.y;
      a2 += b2f(xv[2]) * wv.z;
      a3 += b2f(xv[3]) * wv.w;
    }
  }
  a0 = siluf(a0); a1 = siluf(a1); a2 = siluf(a2); a3 = siluf(a3);
  s16x4 pk; pk[0] = f2b(a0); pk[1] = f2b(a1); pk[2] = f2b(a2); pk[3] = f2b(a3);
  *(s16x4*)(xbc16 + (size_t)row * CONVD_ + c0) = pk;
  if (c0 >= DIN_) {
    int col = c0 - DIN_;
    if (col < 64) *(s16x4*)(B16 + (size_t)row * 64 + col) = pk;
    else          *(s16x4*)(C16 + (size_t)row * 64 + col - 64) = pk;
  }
}

// ============================================================
// SSD prep 1: per-chunk softplus(dt)+cumsum -> dts, lp, Pc
// ============================================================
__global__ __launch_bounds__(256) void ec_ssd_cumsum(
    const short* __restrict__ zx16, const float* __restrict__ dtb,
    const float* __restrict__ Alog, float* __restrict__ dts,
    float* __restrict__ lp, float* __restrict__ Pc)
{
  const int c = blockIdx.x, b = blockIdx.y, hg = blockIdx.z;
  const int t = threadIdx.x;
  const int lane = t & 63, wv = t >> 6;
  const size_t row = (size_t)b * LSEQ_ + (size_t)c * LC_ + t;
  const int h0 = hg * 8;
  __shared__ float wsum[4][8];

  bf16x8 dv = *(const bf16x8*)(zx16 + row * DPROJ_ + (DIN_ + CONVD_) + h0);
  float dt[8], cs[8];
#pragma unroll
  for (int j = 0; j < 8; ++j) {
    float x = b2f(dv[j]) + dtb[h0 + j];
    float sp = (x > 20.f) ? x : log1pf(__expf(x));
    dt[j] = sp;
    cs[j] = sp;
  }
#pragma unroll
  for (int d = 1; d < 64; d <<= 1) {
#pragma unroll
    for (int j = 0; j < 8; ++j) {
      float o = __shfl_up(cs[j], d, 64);
      if (lane >= d) cs[j] += o;
    }
  }
  if (lane == 63)
#pragma unroll
    for (int j = 0; j < 8; ++j) wsum[wv][j] = cs[j];
  __syncthreads();
#pragma unroll
  for (int j = 0; j < 8; ++j) {
    float base = 0.f;
#pragma unroll
    for (int k = 0; k < 3; ++k) if (k < wv) base += wsum[k][j];
    cs[j] += base;
  }
#pragma unroll
  for (int j = 0; j < 8; ++j) {
    int h = h0 + j;
    float lpv = -expf(Alog[h]) * cs[j];
    dts[row * NH_ + h] = dt[j];
    lp[row * NH_ + h] = lpv;
    if (t == LC_ - 1) Pc[(b * NC_ + c) * NH_ + h] = expf(lpv);
  }
}

// ============================================================
// SSD prep 3: VT[b,c,h][p][t] = bf16( dt[t,h] * x[t, h*32+p] )
// ============================================================
__global__ __launch_bounds__(64) void ec_vt(
    const short* __restrict__ xbc16, const float* __restrict__ dts, short* __restrict__ VT)
{
  const int h = blockIdx.x, c = blockIdx.y, b = blockIdx.z;
  const int l = threadIdx.x;
  const size_t rowB = (size_t)b * LSEQ_ + (size_t)c * LC_;
  const size_t vtbase = (size_t)((b * NC_ + c) * NH_ + h) * 32;
  __shared__ float tile[32][33];
  for (int tt = 0; tt < 8; ++tt) {
#pragma unroll
    for (int i = 0; i < 16; ++i) {
      int r = i * 2 + (l >> 5);
      size_t row = rowB + tt * 32 + r;
      tile[r][l & 31] = b2f(xbc16[row * CONVD_ + h * 32 + (l & 31)]) * dts[row * NH_ + h];
    }
    __syncthreads();
#pragma unroll
    for (int j = 0; j < 16; ++j) {
      int p = j * 2 + (l >> 5);
      VT[(vtbase + p) * 256 + tt * 32 + (l & 31)] = f2b(tile[l & 31][p]);
    }
    __syncthreads();
  }
}

// ============================================================
// chunk states: dedicated f32 buffer [b*NC+c][h][32*64]
// ============================================================
__device__ __forceinline__ float* state_ptr(float* stbuf, int b, int c, int h, int e)
{
  return stbuf + ((size_t)((b * NC_ + c) * NH_ + h)) * 2048 + e;
}

// ============================================================
// SSD p1 (MFMA)
// ============================================================
__global__ __launch_bounds__(64) void ec_ssd_p1(
    const short* __restrict__ B16, const short* __restrict__ VT,
    const float* __restrict__ lp, float* __restrict__ stbuf)
{
  const int h = blockIdx.x, c = blockIdx.y, b = blockIdx.z;
  const int l = threadIdx.x, lr = l & 15, lk = l >> 4;
  const size_t rowB = (size_t)b * LSEQ_ + (size_t)c * LC_;
  const size_t vtbase = (size_t)((b * NC_ + c) * NH_ + h) * 32;
  __shared__ short BT[64][264];   // B^T [n][t]
  for (int i = 0; i < 4; ++i) {
    int t = i * 64 + l;
#pragma unroll
    for (int g = 0; g < 8; ++g) {
      bf16x8 v = *(const bf16x8*)&B16[(rowB + t) * 64 + g * 8];
#pragma unroll
      for (int j = 0; j < 8; ++j) BT[g * 8 + j][t] = v[j];
    }
  }
  __syncthreads();
  const float lpE = lp[(rowB + LC_ - 1) * NH_ + h];
  f32x4 acc[2][4];
#pragma unroll
  for (int i = 0; i < 2; ++i)
#pragma unroll
    for (int j = 0; j < 4; ++j) acc[i][j] = f32x4{0.f, 0.f, 0.f, 0.f};

  for (int ks = 0; ks < 8; ++ks) {
    float wv[8];
#pragma unroll
    for (int j = 0; j < 8; ++j) {
      int t = ks * 32 + lk * 8 + j;
      wv[j] = __expf(lpE - lp[(rowB + t) * NH_ + h]);
    }
    bf16x8 af[2];
#pragma unroll
    for (int mf = 0; mf < 2; ++mf) {
      bf16x8 v = *(const bf16x8*)&VT[(vtbase + mf * 16 + lr) * 256 + ks * 32 + lk * 8];
#pragma unroll
      for (int j = 0; j < 8; ++j) af[mf][j] = f2b(b2f(v[j]) * wv[j]);
    }
#pragma unroll
    for (int nf = 0; nf < 4; ++nf) {
      bf16x8 bf = *(const bf16x8*)&BT[nf * 16 + lr][ks * 32 + lk * 8];
#pragma unroll
      for (int mf = 0; mf < 2; ++mf)
        acc[mf][nf] = __builtin_amdgcn_mfma_f32_16x16x32_bf16(af[mf], bf, acc[mf][nf], 0, 0, 0);
    }
  }
#pragma unroll
  for (int mf = 0; mf < 2; ++mf)
#pragma unroll
    for (int nf = 0; nf < 4; ++nf)
#pragma unroll
      for (int r = 0; r < 4; ++r) {
        int p = mf * 16 + lk * 4 + r, n = nf * 16 + lr;
        *state_ptr(stbuf, b, c, h, p * 64 + n) = acc[mf][nf][r];
      }
}

// ============================================================
// SSD p2: sequential prefix over chunks
// ============================================================
__global__ __launch_bounds__(512) void ec_scan_p2(
    float* __restrict__ stbuf, const float* __restrict__ Pc)
{
  const int h = blockIdx.x, b = blockIdx.y;
  const int tid = threadIdx.x;
  const int e = (tid >> 4) * 64 + (tid & 15) * 4;
  float h0 = 0.f, h1 = 0.f, h2 = 0.f, h3 = 0.f;
  for (int c = 0; c < NC_; ++c) {
    float* ptr = state_ptr(stbuf, b, c, h, e);
    float4 S = *(float4*)ptr;
    *(float4*)ptr = make_float4(h0, h1, h2, h3);
    float P = Pc[(b * NC_ + c) * NH_ + h];
    h0 = h0 * P + S.x;
    h1 = h1 * P + S.y;
    h2 = h2 * P + S.z;
    h3 = h3 * P + S.w;
  }
}

// ============================================================
// SSD p3 (MFMA, flash-like)
// ============================================================
__global__ __launch_bounds__(256) void ec_ssd_p3(
    const short* __restrict__ B16, const short* __restrict__ C16,
    const short* __restrict__ VT, const float* __restrict__ lp,
    const short* __restrict__ xbc16, const float* __restrict__ Dp,
    float* __restrict__ stbuf, short* __restrict__ y16)
{
  const int h = blockIdx.x, c = blockIdx.y, b = blockIdx.z;
  const int tid = threadIdx.x;
  const int w = tid >> 6, l = tid & 63, lr = l & 15, lk = l >> 4;
  const size_t rowB = (size_t)b * LSEQ_ + (size_t)c * LC_;
  const size_t vtbase = (size_t)((b * NC_ + c) * NH_ + h) * 32;
  __shared__ short hI[32][72];
  __shared__ short Pl[4][64][72];

  for (int i = tid; i < 2048; i += 256)
    hI[i >> 6][i & 63] = f2b(*state_ptr(stbuf, b, c, h, i));
  __syncthreads();

  const int t0 = w * 64;
  bf16x8 cf[4][2];
#pragma unroll
  for (int tf = 0; tf < 4; ++tf)
#pragma unroll
    for (int ks = 0; ks < 2; ++ks)
      cf[tf][ks] = *(const bf16x8*)&C16[(rowB + t0 + tf * 16 + lr) * 64 + ks * 32 + lk * 8];

  // Y1 = C @ hInit^T
  f32x4 Y[4][2];
#pragma unroll
  for (int i = 0; i < 4; ++i)
#pragma unroll
    for (int j = 0; j < 2; ++j) Y[i][j] = f32x4{0.f, 0.f, 0.f, 0.f};
#pragma unroll
  for (int nf = 0; nf < 2; ++nf)
#pragma unroll
    for (int ks = 0; ks < 2; ++ks) {
      bf16x8 hf = *(const bf16x8*)&hI[nf * 16 + lr][ks * 32 + lk * 8];
#pragma unroll
      for (int mf = 0; mf < 4; ++mf)
        Y[mf][nf] = __builtin_amdgcn_mfma_f32_16x16x32_bf16(cf[mf][ks], hf, Y[mf][nf], 0, 0, 0);
    }
#pragma unroll
  for (int mf = 0; mf < 4; ++mf)
#pragma unroll
    for (int r = 0; r < 4; ++r) {
      float e = __expf(lp[(rowB + t0 + mf * 16 + lk * 4 + r) * NH_ + h]);
      Y[mf][0][r] *= e;
      Y[mf][1][r] *= e;
    }
  float tlp[4];
#pragma unroll
  for (int tf = 0; tf < 4; ++tf)
    tlp[tf] = lp[(rowB + t0 + tf * 16 + lr) * NH_ + h];

  for (int st = 0; st <= w; ++st) {
    const int s0 = st * 64;
#pragma unroll
    for (int half = 0; half < 2; ++half) {
      f32x4 ST[2][4];
#pragma unroll
      for (int i = 0; i < 2; ++i)
#pragma unroll
        for (int j = 0; j < 4; ++j) ST[i][j] = f32x4{0.f, 0.f, 0.f, 0.f};
#pragma unroll
      for (int sf2 = 0; sf2 < 2; ++sf2) {
        int sf = half * 2 + sf2;
#pragma unroll
        for (int ks = 0; ks < 2; ++ks) {
          bf16x8 bfr = *(const bf16x8*)&B16[(rowB + s0 + sf * 16 + lr) * 64 + ks * 32 + lk * 8];
#pragma unroll
          for (int tf = 0; tf < 4; ++tf)
            ST[sf2][tf] = __builtin_amdgcn_mfma_f32_16x16x32_bf16(bfr, cf[tf][ks], ST[sf2][tf], 0, 0, 0);
        }
      }
#pragma unroll
      for (int sf2 = 0; sf2 < 2; ++sf2) {
        int sf = half * 2 + sf2;
        float slp[4];
#pragma unroll
        for (int r = 0; r < 4; ++r)
          slp[r] = lp[(rowB + s0 + sf * 16 + lk * 4 + r) * NH_ + h];
#pragma unroll
        for (int tf = 0; tf < 4; ++tf) {
          float pv[4];
#pragma unroll
          for (int r = 0; r < 4; ++r) {
            pv[r] = ST[sf2][tf][r] * __expf(tlp[tf] - slp[r]);
            if (st == w && (sf * 16 + lk * 4 + r) > (tf * 16 + lr)) pv[r] = 0.f;
          }
          union { float f; unsigned u; } q0, q1, q2, q3;
          q0.f = pv[0]; q1.f = pv[1]; q2.f = pv[2]; q3.f = pv[3];
          uint2 pk;
          pk.x = (q0.u >> 16) | (q1.u & 0xffff0000u);
          pk.y = (q2.u >> 16) | (q3.u & 0xffff0000u);
          *(uint2*)&Pl[w][tf * 16 + lr][sf * 16 + lk * 4] = pk;
        }
      }
    }
    // wave-private LDS write->read fence (rule #18)
    __builtin_amdgcn_sched_barrier(0);
    asm volatile("s_waitcnt lgkmcnt(0)" ::: "memory");
    __builtin_amdgcn_sched_barrier(0);
#pragma unroll
    for (int ks = 0; ks < 2; ++ks) {
      bf16x8 vf[2];
#pragma unroll
      for (int nf = 0; nf < 2; ++nf)
        vf[nf] = *(const bf16x8*)&VT[(vtbase + nf * 16 + lr) * 256 + s0 + ks * 32 + lk * 8];
#pragma unroll
      for (int mf = 0; mf < 4; ++mf) {
        bf16x8 pf = *(const bf16x8*)&Pl[w][mf * 16 + lr][ks * 32 + lk * 8];
#pragma unroll
        for (int nf = 0; nf < 2; ++nf)
          Y[mf][nf] = __builtin_amdgcn_mfma_f32_16x16x32_bf16(pf, vf[nf], Y[mf][nf], 0, 0, 0);
      }
    }
  }
  // epilogue with D*x
  const float Dh = Dp[h];
#pragma unroll
  for (int mf = 0; mf < 4; ++mf)
#pragma unroll
    for (int r = 0; r < 4; ++r) {
      size_t yrow = rowB + t0 + mf * 16 + lk * 4 + r;
#pragma unroll
      for (int nf = 0; nf < 2; ++nf) {
        float xv = b2f(xbc16[yrow * CONVD_ + h * 32 + nf * 16 + lr]);
        y16[yrow * DIN_ + h * 32 + nf * 16 + lr] = f2b(Y[mf][nf][r] + Dh * xv);
      }
    }
}

// ============================================================
// t = y * silu(z); out = rmsnorm(t)*nw -> bf16 (row width 1024)
// ============================================================
__global__ __launch_bounds__(256) void ec_gate_rms16(
    const short* __restrict__ y16, const short* __restrict__ zx16,
    const float* __restrict__ nw, short* __restrict__ out)
{
  const int row = blockIdx.x;
  const int c0 = threadIdx.x * 4;
  s16x4 yv = *(const s16x4*)(y16 + (size_t)row * DIN_ + c0);
  s16x4 zv = *(const s16x4*)(zx16 + (size_t)row * DPROJ_ + c0);
  float v[4]; float ss = 0.f;
#pragma unroll
  for (int j = 0; j < 4; ++j) {
    float t = b2f(yv[j]) * siluf(b2f(zv[j]));
    v[j] = t; ss += t * t;
  }
#pragma unroll
  for (int m = 32; m >= 1; m >>= 1) ss += __shfl_xor(ss, m, 64);
  __shared__ float buf[4];
  if ((threadIdx.x & 63) == 0) buf[threadIdx.x >> 6] = ss;
  __syncthreads();
  ss = buf[0] + buf[1] + buf[2] + buf[3];
  float scale = rsqrtf(ss / (float)DIN_ + 1e-5f);
  float4 wv = *(const float4*)(nw + c0);
  s16x4 ov;
  ov[0] = f2b(v[0] * scale * wv.x);
  ov[1] = f2b(v[1] * scale * wv.y);
  ov[2] = f2b(v[2] * scale * wv.z);
  ov[3] = f2b(v[3] * scale * wv.w);
  *(s16x4*)(out + (size_t)row * DIN_ + c0) = ov;
}

// ============================================================
// out = rmsnorm(a16 + b)*w -> fp32 + bf16 (row width 512, a is bf16)
// ============================================================
__global__ __launch_bounds__(128) void ec_rmsadd16(
    const short* __restrict__ a16, const float* __restrict__ bres,
    const float* __restrict__ w, float* __restrict__ out, short* __restrict__ out16)
{
  const int row = blockIdx.x;
  const int c0 = threadIdx.x * 4;
  s16x4 av = *(const s16x4*)(a16 + (size_t)row * HID_ + c0);
  float4 brv = *(const float4*)(bres + (size_t)row * HID_ + c0);
  float v[4]; float ss = 0.f;
  v[0] = b2f(av[0]) + brv.x; v[1] = b2f(av[1]) + brv.y;
  v[2] = b2f(av[2]) + brv.z; v[3] = b2f(av[3]) + brv.w;
#pragma unroll
  for (int j = 0; j < 4; ++j) ss += v[j] * v[j];
#pragma unroll
  for (int m = 32; m >= 1; m >>= 1) ss += __shfl_xor(ss, m, 64);
  __shared__ float buf[2];
  if ((threadIdx.x & 63) == 0) buf[threadIdx.x >> 6] = ss;
  __syncthreads();
  ss = buf[0] + buf[1];
  float scale = rsqrtf(ss / (float)HID_ + 1e-5f);
  float4 wv = *(const float4*)(w + c0);
  float o0 = v[0] * scale * wv.x, o1 = v[1] * scale * wv.y;
  float o2 = v[2] * scale * wv.z, o3 = v[3] * scale * wv.w;
  *(float4*)(out + (size_t)row * HID_ + c0) = make_float4(o0, o1, o2, o3);
  s16x4 ov; ov[0] = f2b(o0); ov[1] = f2b(o1); ov[2] = f2b(o2); ov[3] = f2b(o3);
  *(s16x4*)(out16 + (size_t)row * HID_ + c0) = ov;
}

// ============================================================
// layernorm(in)*w + b -> fp32 (+ optional bf16) (row width 512)
// ============================================================
__global__ __launch_bounds__(128) void ec_ln16(
    const float* __restrict__ in, const float* __restrict__ w,
    const float* __restrict__ bb, float* __restrict__ out, short* __restrict__ out16)
{
  const int row = blockIdx.x;
  const float* ir = in + (size_t)row * HID_;
  float v[4]; float s = 0.f, s2 = 0.f;
#pragma unroll
  for (int j = 0; j < 4; ++j) {
    int c = j * 128 + threadIdx.x;
    float t = ir[c];
    v[j] = t; s += t; s2 += t * t;
  }
#pragma unroll
  for (int m = 32; m >= 1; m >>= 1) { s += __shfl_xor(s, m, 64); s2 += __shfl_xor(s2, m, 64); }
  __shared__ float buf[4];
  if ((threadIdx.x & 63) == 0) { int wi = threadIdx.x >> 6; buf[wi * 2] = s; buf[wi * 2 + 1] = s2; }
  __syncthreads();
  s = buf[0] + buf[2]; s2 = buf[1] + buf[3];
  float mean = s / (float)HID_;
  float var = s2 / (float)HID_ - mean * mean;
  float inv = rsqrtf(var + 1e-5f);
#pragma unroll
  for (int j = 0; j < 4; ++j) {
    int c = j * 128 + threadIdx.x;
    float o = (v[j] - mean) * inv * w[c] + bb[c];
    out[(size_t)row * HID_ + c] = o;
    if (out16) out16[(size_t)row * HID_ + c] = f2b(o);
  }
}

// ============================================================
// fused double layernorm: out = LN2(LN1(in)) (row width 512)
// ============================================================
__global__ __launch_bounds__(128) void ec_ln2x(
    const float* __restrict__ in, const float* __restrict__ w1,
    const float* __restrict__ bb1, const float* __restrict__ w2,
    const float* __restrict__ bb2, float* __restrict__ out)
{
  const int row = blockIdx.x;
  const float* ir = in + (size_t)row * HID_;
  float v[4]; float s = 0.f, s2 = 0.f;
#pragma unroll
  for (int j = 0; j < 4; ++j) {
    int c = j * 128 + threadIdx.x;
    float t = ir[c];
    v[j] = t; s += t; s2 += t * t;
  }
#pragma unroll
  for (int m = 32; m >= 1; m >>= 1) { s += __shfl_xor(s, m, 64); s2 += __shfl_xor(s2, m, 64); }
  __shared__ float buf[4];
  if ((threadIdx.x & 63) == 0) { int wi = threadIdx.x >> 6; buf[wi * 2] = s; buf[wi * 2 + 1] = s2; }
  __syncthreads();
  s = buf[0] + buf[2]; s2 = buf[1] + buf[3];
  float mean = s / (float)HID_;
  float var = s2 / (float)HID_ - mean * mean;
  float inv = rsqrtf(var + 1e-5f);
  float o[4]; float t1 = 0.f, t2 = 0.f;
#pragma unroll
  for (int j = 0; j < 4; ++j) {
    int c = j * 128 + threadIdx.x;
    float t = (v[j] - mean) * inv * w1[c] + bb1[c];
    o[j] = t; t1 += t; t2 += t * t;
  }
#pragma unroll
  for (int m = 32; m >= 1; m >>= 1) { t1 += __shfl_xor(t1, m, 64); t2 += __shfl_xor(t2, m, 64); }
  __syncthreads();
  if ((threadIdx.x & 63) == 0) { int wi = threadIdx.x >> 6; buf[wi * 2] = t1; buf[wi * 2 + 1] = t2; }
  __syncthreads();
  t1 = buf[0] + buf[2]; t2 = buf[1] + buf[3];
  float mean2 = t1 / (float)HID_;
  float var2 = t2 / (float)HID_ - mean2 * mean2;
  float inv2 = rsqrtf(var2 + 1e-5f);
#pragma unroll
  for (int j = 0; j < 4; ++j) {
    int c = j * 128 + threadIdx.x;
    out[(size_t)row * HID_ + c] = (o[j] - mean2) * inv2 * w2[c] + bb2[c];
  }
}

// ============================================================
// MFMA flash attention, 128-row Q tile, 8 waves, KV-split (NS_=8),
// defer-max, bf16 partials, tile-major V^T input, DOUBLE-BUFFERED K/V
// (one barrier per K-tile: stage t+1 into buf^1 while computing buf).
// grid (LT_/128, NHEAD_, BB_*NS_), 512 threads.
// ============================================================
__global__ __launch_bounds__(512) void ec_attn16(
    const short* __restrict__ qkv, const short* __restrict__ vt16,
    short* __restrict__ Op, float2* __restrict__ ml)
{
  const int b = blockIdx.z & 1, split = blockIdx.z >> 1;
  const int h = blockIdx.y, qt = blockIdx.x;
  __shared__ short Kl[2][64 * 68];
  __shared__ short Vl[2][64 * 68];
  __shared__ short Pl[128 * 68];
  const int tid = threadIdx.x;
  const int l = tid & 63, w = tid >> 6;   // 8 waves, wave w owns q rows w*16..+16
  const int lr = l & 15, lk = l >> 4;

  const size_t qrow = (size_t)b * LT_ + qt * 128 + w * 16 + lr;
  bf16x8 qf[2];
  qf[0] = *(const bf16x8*)&qkv[qrow * 1536 + h * HD_ + lk * 8];
  qf[1] = *(const bf16x8*)&qkv[qrow * 1536 + h * HD_ + lk * 8 + 32];

  float mrun[4] = {-1e30f, -1e30f, -1e30f, -1e30f};
  float lsum[4] = {0.f, 0.f, 0.f, 0.f};
  f32x4 O[4];
#pragma unroll
  for (int df = 0; df < 4; ++df) O[df] = f32x4{0.f, 0.f, 0.f, 0.f};

  const int krow = tid >> 3, kcg = (tid & 7) * 8;   // K: 512 thr x 16B = 8KB tile
  const short* vtile = vt16 + (size_t)(b * NHEAD_ + h) * (LT_ / 64) * 4096;
  const int vofs = tid * 8;
  const int vlds = (tid >> 3) * 68 + (tid & 7) * 8;

  auto stageKV = [&](int kt, int bufi) {
    const size_t krbase = (size_t)b * LT_ + kt * 64;
    const short* kp = &qkv[(krbase + krow) * 1536 + HID_ + h * HD_ + kcg];
    *(bf16x8*)&Kl[bufi][krow * 68 + kcg] = *(const bf16x8*)kp;
    bf16x8 vv = *(const bf16x8*)&vtile[(size_t)kt * 4096 + vofs];
    *(bf16x8*)&Vl[bufi][vlds] = vv;
  };

  stageKV(split * KTS_, 0);
  __syncthreads();

  for (int i = 0; i < KTS_; ++i) {
    const int cur = i & 1;
    if (i + 1 < KTS_) stageKV(split * KTS_ + i + 1, cur ^ 1);

    f32x4 S[4];
#pragma unroll
    for (int nf = 0; nf < 4; ++nf) S[nf] = f32x4{0.f, 0.f, 0.f, 0.f};
#pragma unroll
    for (int ks = 0; ks < 2; ++ks)
#pragma unroll
      for (int nf = 0; nf < 4; ++nf) {
        bf16x8 kb = *(const bf16x8*)&Kl[cur][(nf * 16 + lr) * 68 + ks * 32 + lk * 8];
        S[nf] = __builtin_amdgcn_mfma_f32_16x16x32_bf16(qf[ks], kb, S[nf], 0, 0, 0);
      }

    // defer-max: scores already scaled; skip rescale unless growth > 8
    int ok = 1;
#pragma unroll
    for (int nf = 0; nf < 4; ++nf)
#pragma unroll
      for (int r = 0; r < 4; ++r)
        ok &= (S[nf][r] <= mrun[r] + 8.f);
    if (!__all(ok)) {
      float fr[4];
#pragma unroll
      for (int r = 0; r < 4; ++r) {
        float mt = fmaxf(fmaxf(S[0][r], S[1][r]), fmaxf(S[2][r], S[3][r]));
        mt = fmaxf(mt, __shfl_xor(mt, 1));
        mt = fmaxf(mt, __shfl_xor(mt, 2));
        mt = fmaxf(mt, __shfl_xor(mt, 4));
        mt = fmaxf(mt, __shfl_xor(mt, 8));
        float mn = fmaxf(mrun[r], mt);
        fr[r] = __expf(mrun[r] - mn);
        mrun[r] = mn;
        lsum[r] *= fr[r];
      }
#pragma unroll
      for (int df = 0; df < 4; ++df) {
        O[df][0] *= fr[0]; O[df][1] *= fr[1]; O[df][2] *= fr[2]; O[df][3] *= fr[3];
      }
    }
#pragma unroll
    for (int nf = 0; nf < 4; ++nf)
#pragma unroll
      for (int r = 0; r < 4; ++r) {
        float p = __expf(S[nf][r] - mrun[r]);
        lsum[r] += p;
        Pl[(w * 16 + lk * 4 + r) * 68 + nf * 16 + lr] = f2bt(p);
      }

#pragma unroll
    for (int ks = 0; ks < 2; ++ks) {
      bf16x8 pa = *(const bf16x8*)&Pl[(w * 16 + lr) * 68 + ks * 32 + lk * 8];
#pragma unroll
      for (int df = 0; df < 4; ++df) {
        bf16x8 vb = *(const bf16x8*)&Vl[cur][(df * 16 + lr) * 68 + ks * 32 + lk * 8];
        O[df] = __builtin_amdgcn_mfma_f32_16x16x32_bf16(pa, vb, O[df], 0, 0, 0);
      }
    }
    __syncthreads();
  }

#pragma unroll
  for (int r = 0; r < 4; ++r) {
    lsum[r] += __shfl_xor(lsum[r], 1);
    lsum[r] += __shfl_xor(lsum[r], 2);
    lsum[r] += __shfl_xor(lsum[r], 4);
    lsum[r] += __shfl_xor(lsum[r], 8);
  }
  const size_t sstride = (size_t)BB_ * NHEAD_ * LT_;
  const size_t obase = (size_t)split * sstride + ((size_t)b * NHEAD_ + h) * LT_ + qt * 128 + w * 16;
#pragma unroll
  for (int df = 0; df < 4; ++df)
#pragma unroll
    for (int r = 0; r < 4; ++r)
      Op[(obase + lk * 4 + r) * 64 + df * 16 + lr] = f2b(O[df][r]);
  if (lr == 0)
#pragma unroll
    for (int r = 0; r < 4; ++r)
      ml[obase + lk * 4 + r] = make_float2(mrun[r], lsum[r]);
}

// ============================================================
// attention split-combine (bf16 partials)
// ============================================================
__global__ __launch_bounds__(256) void ec_attn_comb(
    const short* __restrict__ Op, const float2* __restrict__ ml, short* __restrict__ out)
{
  const int qt = blockIdx.x, h = blockIdx.y, b = blockIdx.z;
  const int r = threadIdx.x >> 2, c0 = (threadIdx.x & 3) * 16;
  const int qrow = qt * 64 + r;
  const size_t sstride = (size_t)BB_ * NHEAD_ * LT_;
  const size_t rb = ((size_t)b * NHEAD_ + h) * LT_ + qrow;
  float m[NS_], lv[NS_];
  float mmax = -1e30f;
#pragma unroll
  for (int s = 0; s < NS_; ++s) {
    float2 v = ml[rb + s * sstride];
    m[s] = v.x; lv[s] = v.y;
    mmax = fmaxf(mmax, m[s]);
  }
  float den = 0.f, wsc[NS_];
#pragma unroll
  for (int s = 0; s < NS_; ++s) { wsc[s] = __expf(m[s] - mmax); den += lv[s] * wsc[s]; }
  float inv = 1.f / den;
  float o[16];
#pragma unroll
  for (int i = 0; i < 16; ++i) o[i] = 0.f;
#pragma unroll
  for (int s = 0; s < NS_; ++s) {
    const short* p = Op + (rb + s * sstride) * 64 + c0;
    float wq = wsc[s];
#pragma unroll
    for (int i = 0; i < 4; ++i) {
      s16x4 v = *(const s16x4*)(p + i * 4);
      o[i * 4 + 0] += b2f(v[0]) * wq; o[i * 4 + 1] += b2f(v[1]) * wq;
      o[i * 4 + 2] += b2f(v[2]) * wq; o[i * 4 + 3] += b2f(v[3]) * wq;
    }
  }
  short* op = out + ((size_t)b * LT_ + qrow) * HID_ + h * HD_ + c0;
#pragma unroll
  for (int i = 0; i < 16; ++i) op[i] = f2b(o[i] * inv);
}

// ============================================================
// host launch
// ============================================================
extern "C" void kernel_launch(void* const* d_in, const int* in_sizes, int n_in,
                              void* d_out, int out_size, void* d_ws, size_t ws_size,
                              hipStream_t stream)
{
  const float* x_in   = (const float*)d_in[0];
  const float* Wp     = (const float*)d_in[1];
  const float* bp     = (const float*)d_in[2];
  const float* m_Wi[2]   = {(const float*)d_in[3],  (const float*)d_in[11]};
  const float* m_cw[2]   = {(const float*)d_in[4],  (const float*)d_in[12]};
  const float* m_cb[2]   = {(const float*)d_in[5],  (const float*)d_in[13]};
  const float* m_dtb[2]  = {(const float*)d_in[6],  (const float*)d_in[14]};
  const float* m_Alog[2] = {(const float*)d_in[7],  (const float*)d_in[15]};
  const float* m_D[2]    = {(const float*)d_in[8],  (const float*)d_in[16]};
  const float* m_nw[2]   = {(const float*)d_in[9],  (const float*)d_in[17]};
  const float* m_Wo[2]   = {(const float*)d_in[10], (const float*)d_in[18]};
  const float* n_w[2]    = {(const float*)d_in[19], (const float*)d_in[20]};
  const float* ds_w   = (const float*)d_in[21];
  const float* ds_b   = (const float*)d_in[22];
  const float* t_Wqkv = (const float*)d_in[23];
  const float* t_bqkv = (const float*)d_in[24];
  const float* t_Wo   = (const float*)d_in[25];
  const float* t_bo   = (const float*)d_in[26];
  const float* t_W1   = (const float*)d_in[27];
  const float* t_b1   = (const float*)d_in[28];
  const float* t_W2   = (const float*)d_in[29];
  const float* t_b2   = (const float*)d_in[30];
  const float* t_ln1w = (const float*)d_in[31];
  const float* t_ln1b = (const float*)d_in[32];
  const float* t_ln2w = (const float*)d_in[33];
  const float* t_ln2b = (const float*)d_in[34];
  const float* on_w   = (const float*)d_in[35];
  const float* on_b   = (const float*)d_in[36];

  char* ws = (char*)d_ws;
  float* bx    = (float*)(ws + 0);                    // [8192,512] f32 residual
  short* zx16  = (short*)(ws + 16777216);             // [8192,2208] bf16 zxbcdt
  float* stbuf = (float*)(ws + 16777216 + 36175872);  // [1024][2048] f32 chunk states
  short* xbc16 = (short*)(ws + 89128960);             // [8192,1152] bf16 xBC
  short* y16   = (short*)(ws + 126877696);            // [8192,1024] bf16 scan y
  short* VT    = (short*)(ws + 143654912);            // [b,c,h][32][256] bf16 dtx^T
  float* lp    = (float*)(ws + 160432128);            // [8192,32] log-decay prefix
  float* dts   = (float*)(ws + 161480704);            // [8192,32] dt
  short* wslot = (short*)(ws + 162529280);            // bf16 weight slot / B16+C16
  float* Pc    = (float*)(ws + 165150720);            // 4 KB
  float* cwt   = (float*)(ws + 165154816);            // [4][1152] f32 transposed conv w

  short* B16 = wslot;                          // [8192,64] bf16 (scan window only)
  short* C16 = wslot + 524288;                 // [8192,64]
  short* a16buf = (short*)(ws + 126877696);    // out-proj bf16 out (over dead y16)

  short* x16     = (short*)(ws + 126877696);   // input bf16 (dead before p3)
  short* bx16    = (short*)(ws + 89128960);    // residual bf16 (time-mux with xbc16)
  short* gated16 = (short*)(ws + 89128960 + 18874368);

  short*  Opart = (short*)(ws + 89128960);                 // NS*B*H*LT*64 bf16 = 33.5 MB
  float2* mlbuf = (float2*)(ws + 89128960 + 33554432);     // 2 MB

  char* tzone = ws + 16777216;
  short* ds16  = (short*)tzone;
  float* dsf   = (float*)(tzone + 4194304);
  short* qkv16 = (short*)(tzone + 12582912);
  short* att16 = (short*)(tzone + 25165824);
  float* bt1   = (float*)(tzone + 29360128);
  short* ln116 = (short*)(tzone + 37748736);
  float* bxt2  = (float*)(tzone + 41943040);
  short* ff16  = (short*)(tzone + 50331648);
  float* bt2   = (float*)(tzone + 58720256);
  short* vt16  = (short*)(tzone + 67108864);   // [B,H,kt][d*64+key] bf16 V^T (4 MB)

  const int MR = BB_ * LSEQ_;  // 8192
  const int MT = BB_ * LT_;    // 4096

  // input projection (64x64 tile); writes f32 residual + bf16 copy
  ec_f2b<<<(MR * 1024 / 8 + 255) / 256, 256, 0, stream>>>(x_in, x16, MR * 1024 / 8);
  ec_w2bt<<<dim3(1024 / 32, 512 / 32), 256, 0, stream>>>(Wp, wslot, 1024, 512);
  gemm16b(stream, x16, wslot, bp, nullptr, bx, bx16, MR, HID_, 1024, 0);

  for (int blk = 0; blk < 2; ++blk) {
    ec_w2bt<<<dim3(512 / 32, 2208 / 32), 256, 0, stream>>>(m_Wi[blk], wslot, 512, 2208);
    {
      dim3 g((DPROJ_ + 127) / 128, MR / 64), b(256);
      ec_gemm16bw<<<g, b, 0, stream>>>(bx16, wslot, nullptr, zx16, nullptr,
                                       MR, DPROJ_, HID_, 0);
    }
    ec_cwt<<<(CONVD_ * 4 + 255) / 256, 256, 0, stream>>>(m_cw[blk], cwt);
    ec_conv1d_silu<<<(MR * (CONVD_ / 4) + 255) / 256, 256, 0, stream>>>(
        zx16, cwt, m_cb[blk], xbc16, B16, C16);
    ec_ssd_cumsum<<<dim3(NC_, BB_, NH_ / 8), 256, 0, stream>>>(zx16, m_dtb[blk], m_Alog[blk], dts, lp, Pc);
    ec_vt<<<dim3(NH_, NC_, BB_), 64, 0, stream>>>(xbc16, dts, VT);
    ec_ssd_p1<<<dim3(NH_, NC_, BB_), 64, 0, stream>>>(B16, VT, lp, stbuf);
    ec_scan_p2<<<dim3(NH_, BB_), 512, 0, stream>>>(stbuf, Pc);
    ec_ssd_p3<<<dim3(NH_, NC_, BB_), 256, 0, stream>>>(B16, C16, VT, lp, xbc16, m_D[blk], stbuf, y16);
    ec_gate_rms16<<<MR, 256, 0, stream>>>(y16, zx16, m_nw[blk], gated16);
    ec_w2bt<<<dim3(1024 / 32, 512 / 32), 256, 0, stream>>>(m_Wo[blk], wslot, 1024, 512);
    gemm16b(stream, gated16, wslot, nullptr, nullptr, nullptr, a16buf, MR, HID_, DIN_, 0);
    ec_rmsadd16<<<MR, 128, 0, stream>>>(a16buf, bx, n_w[blk], bx, bx16);
  }

  // downsample conv as implicit-im2col GEMM (64x64 tile)
  ec_dswt<<<(HID_ * 1536 + 255) / 256, 256, 0, stream>>>(ds_w, wslot);
  {
    dim3 g(512 / 64, LT_ / 64, BB_), b(256);
    ec_gemm16b<<<g, b, 0, stream>>>(bx16 - 512, wslot, ds_b, nullptr, dsf, ds16,
                                    LT_, HID_, 1536, 0, 1024, (long)LSEQ_ * HID_, LT_);
  }
  ec_dsfix<<<BB_, 512, 0, stream>>>(bx16, wslot, ds_b, dsf, ds16);

  // transformer layer; qkv GEMM (64x128 tile) pre-scales q cols by 0.125 and
  // writes the V slice tile-major transposed into vt16 (Cv path).
  ec_w2bt<<<dim3(512 / 32, 1536 / 32), 256, 0, stream>>>(t_Wqkv, wslot, 512, 1536);
  {
    dim3 g(1536 / 128, MT / 64), b(256);
    ec_gemm16bw<<<g, b, 0, stream>>>(ds16, wslot, t_bqkv, qkv16, vt16,
                                     MT, 3 * HID_, HID_, 2);
  }
  ec_attn16<<<dim3(LT_ / 128, NHEAD_, BB_ * NS_), 512, 0, stream>>>(qkv16, vt16, Opart, mlbuf);
  ec_attn_comb<<<dim3(LT_ / 64, NHEAD_, BB_), 256, 0, stream>>>(Opart, mlbuf, att16);
  ec_w2bt<<<dim3(512 / 32, 512 / 32), 256, 0, stream>>>(t_Wo, wslot, 512, 512);
  gemm16b(stream, att16, wslot, t_bo, dsf, bt1, nullptr, MT, HID_, HID_, 0);
  ec_ln16<<<MT, 128, 0, stream>>>(bt1, t_ln1w, t_ln1b, bxt2, ln116);
  ec_w2bt<<<dim3(512 / 32, 1024 / 32), 256, 0, stream>>>(t_W1, wslot, 512, 1024);
  {
    dim3 g(DFF_ / 128, MT / 64), b(256);
    ec_gemm16bw<<<g, b, 0, stream>>>(ln116, wslot, t_b1, ff16, nullptr,
                                     MT, DFF_, HID_, 1);
  }
  ec_w2bt<<<dim3(1024 / 32, 512 / 32), 256, 0, stream>>>(t_W2, wslot, 1024, 512);
  gemm16b(stream, ff16, wslot, t_b2, bxt2, bt2, nullptr, MT, HID_, DFF_, 0);
  ec_ln2x<<<MT, 128, 0, stream>>>(bt2, t_ln2w, t_ln2b, on_w, on_b, (float*)d_out);
}

// Round 25
// 548.703 us; speedup vs baseline: 1.1143x; 1.1143x over previous
//
#include <hip/hip_runtime.h>
#include <math.h>

// ---- model dims ----
#define DIN_   1024
#define DSTATE_ 64
#define NH_    32
#define HDIM_  32
#define CONVD_ 1152   // DIN + 2*DSTATE
#define DPROJ_ 2208   // 2*DIN + 2*DSTATE + NH
#define HID_   512
#define LSEQ_  4096
#define BB_    2
#define LT_    2048   // after stride-2 downsample
#define NHEAD_ 8
#define HD_    64     // head dim = 512/8
#define DFF_   1024
#define LC_    256    // scan chunk length
#define NC_    16     // number of chunks (LSEQ_/LC_)
#define NS_    8      // attention KV splits
#define KTS_   (LT_ / 64 / NS_)   // 4 K-tiles per split

typedef __attribute__((ext_vector_type(8))) short bf16x8;
typedef __attribute__((ext_vector_type(4))) short s16x4;
typedef __attribute__((ext_vector_type(4))) float f32x4;

__device__ __forceinline__ float siluf(float x) { return x / (1.f + __expf(-x)); }

__device__ __forceinline__ short f2b(float f) {
  union { float f; unsigned u; } v; v.f = f;
  unsigned r = (v.u + 0x7fffu + ((v.u >> 16) & 1u)) >> 16;
  return (short)r;
}

// truncation bf16 (1 op) — for internal P matrices only
__device__ __forceinline__ short f2bt(float f) {
  union { float f; unsigned u; } v; v.f = f;
  return (short)(v.u >> 16);
}

__device__ __forceinline__ float b2f(short s) {
  union { unsigned u; float f; } v; v.u = ((unsigned)(unsigned short)s) << 16;
  return v.f;
}

// async global->LDS 16B per lane; lds base must be wave-uniform
__device__ __forceinline__ void gload16(const short* g, short* lds_base) {
#if __has_builtin(__builtin_amdgcn_global_load_lds)
  __builtin_amdgcn_global_load_lds((const __attribute__((address_space(1))) void*)g,
                                   (__attribute__((address_space(3))) void*)lds_base, 16, 0, 0);
#else
  int l = threadIdx.x & 63;
  ((bf16x8*)lds_base)[l] = *(const bf16x8*)g;
#endif
}

// XCD-aware bijective block-id swizzle (m204 form)
__device__ __forceinline__ void xcd_swz(int& bx, int& by, int& bz) {
  int nbx = gridDim.x, nby = gridDim.y;
  int nwg = nbx * nby * gridDim.z;
  int orig = (blockIdx.z * nby + blockIdx.y) * nbx + blockIdx.x;
  int q = nwg >> 3, r = nwg & 7;
  int xcd = orig & 7, lin = orig >> 3;
  int wg = (xcd < r ? xcd * (q + 1) : r * (q + 1) + (xcd - r) * q) + lin;
  bx = wg % nbx; wg /= nbx;
  by = wg % nby;
  bz = wg / nby;
}

// ============================================================
// fp32 -> bf16 elementwise (8 per thread)
// ============================================================
__global__ void ec_f2b(const float* __restrict__ in, short* __restrict__ out, int n8)
{
  int i = blockIdx.x * 256 + threadIdx.x;
  if (i >= n8) return;
  const float4* p = (const float4*)(in + (size_t)i * 8);
  float4 a = p[0], b = p[1];
  bf16x8 o;
  o[0] = f2b(a.x); o[1] = f2b(a.y); o[2] = f2b(a.z); o[3] = f2b(a.w);
  o[4] = f2b(b.x); o[5] = f2b(b.y); o[6] = f2b(b.z); o[7] = f2b(b.w);
  *(bf16x8*)(out + (size_t)i * 8) = o;
}

// ============================================================
// weight convert+transpose: W fp32 [K,N] -> Wt bf16 [N,K]
// ============================================================
__global__ __launch_bounds__(256) void ec_w2bt(const float* __restrict__ W,
                                               short* __restrict__ Wt, int K, int N)
{
  __shared__ float t[32][33];
  int k0 = blockIdx.x * 32, n0 = blockIdx.y * 32;
  int tx = threadIdx.x & 31, ty = threadIdx.x >> 5;
#pragma unroll
  for (int i = 0; i < 32; i += 8) t[ty + i][tx] = W[(size_t)(k0 + ty + i) * N + n0 + tx];
  __syncthreads();
#pragma unroll
  for (int i = 0; i < 32; i += 8) Wt[(size_t)(n0 + ty + i) * K + k0 + tx] = f2b(t[tx][ty + i]);
}

// ============================================================
// ds_w (O,I,K=3) -> Wt bf16 [O, K*512] with layout Wt[o][k*512+i]
// ============================================================
__global__ void ec_dswt(const float* __restrict__ w, short* __restrict__ wt)
{
  int idx = blockIdx.x * 256 + threadIdx.x;
  if (idx >= HID_ * 1536) return;
  int o = idx / 1536, r = idx % 1536;
  int k = r >> 9, i = r & 511;
  wt[idx] = f2b(w[((size_t)o * HID_ + i) * 3 + k]);
}

// ============================================================
// conv weight transpose: cw [CONVD_][4] -> cwt [4][CONVD_]
// ============================================================
__global__ void ec_cwt(const float* __restrict__ cw, float* __restrict__ cwt)
{
  int idx = blockIdx.x * 256 + threadIdx.x;
  if (idx >= CONVD_ * 4) return;
  int j = idx / CONVD_, c = idx % CONVD_;
  cwt[idx] = cw[c * 4 + j];
}

// ============================================================
// bf16 MFMA GEMM, 64x64 tile, BK=64, 8 WAVES (512 thr): each wave owns
// a 16x32 sub-tile (1 A-frag x 2 B-frags). Same LDS layout/swizzle as
// the 4-wave version (bit-identical staging), but 2x resident waves per
// block -> barrier drains hide under other waves' MFMA.
// act: 0=none, 1=gelu(exact), 2=q-scale 0.125 (+ Cv tile-major V^T write)
// ============================================================
__global__ __launch_bounds__(512) void ec_gemm16b(
    const short* __restrict__ A, const short* __restrict__ Wt,
    const float* __restrict__ bias, const float* __restrict__ res,
    float* __restrict__ Cf, short* __restrict__ Ch, short* __restrict__ Cv,
    int M, int N, int K, int act, int lda, long Az, int Mz)
{
  __shared__ short As_[2][4096];   // [64 rows][64 k] bf16, slot-swizzled
  __shared__ short Bs_[2][4096];
  int bxi, byi, bzi;
  xcd_swz(bxi, byi, bzi);
  A += (size_t)bzi * Az;
  const int mz = bzi * Mz;
  const int tid = threadIdx.x;
  const int l = tid & 63, w = tid >> 6;          // 8 waves
  const int m0 = byi * 64, n0 = bxi * 64;
  const int wm = (w >> 1) * 16, wn = (w & 1) * 32;
  const int lr = l & 15, lk = l >> 4;
  // staging: thread tid covers row tid>>3, 16B slot tid&7; global slot is
  // (tid&7) ^ (row&7) (XOR involution, rule #21). LDS dest stays linear.
  const int srow = tid >> 3;
  const int scol = ((tid & 7) ^ ((tid >> 3) & 7)) * 8;
  // fragment read: global slot g = ksub*4+lk lives at LDS slot g^(row&7),
  // row&7 == lr&7 (wm/wn multiples of 16).
  const int rs0 = ((0 * 4 + lk) ^ (lr & 7)) * 8;
  const int rs1 = ((1 * 4 + lk) ^ (lr & 7)) * 8;

  f32x4 acc[2];
  acc[0] = f32x4{0.f, 0.f, 0.f, 0.f};
  acc[1] = f32x4{0.f, 0.f, 0.f, 0.f};

  // prologue: stage k-tile 0 (each wave loads its 8 rows of A and B)
  {
    const short* ga = A + (size_t)(m0 + srow) * lda + scol;
    int rb = n0 + srow; if (rb > N - 1) rb = N - 1;
    const short* gb = Wt + (size_t)rb * K + scol;
    gload16(ga, &As_[0][w * 512]);
    gload16(gb, &Bs_[0][w * 512]);
  }

  const int KT = K >> 6;
  for (int kt = 0; kt < KT; ++kt) {
    __syncthreads();
    if (kt + 1 < KT) {
      int k0 = (kt + 1) << 6;
      int nb = (kt + 1) & 1;
      const short* ga = A + (size_t)(m0 + srow) * lda + k0 + scol;
      int rb = n0 + srow; if (rb > N - 1) rb = N - 1;
      const short* gb = Wt + (size_t)rb * K + k0 + scol;
      gload16(ga, &As_[nb][w * 512]);
      gload16(gb, &Bs_[nb][w * 512]);
    }
    int cb = kt & 1;
#pragma unroll
    for (int ksub = 0; ksub < 2; ++ksub) {
      const int rs = ksub ? rs1 : rs0;
      bf16x8 af = *(const bf16x8*)&As_[cb][(wm + lr) * 64 + rs];
      bf16x8 b0 = *(const bf16x8*)&Bs_[cb][(wn + lr) * 64 + rs];
      bf16x8 b1 = *(const bf16x8*)&Bs_[cb][(wn + 16 + lr) * 64 + rs];
      acc[0] = __builtin_amdgcn_mfma_f32_16x16x32_bf16(af, b0, acc[0], 0, 0, 0);
      acc[1] = __builtin_amdgcn_mfma_f32_16x16x32_bf16(af, b1, acc[1], 0, 0, 0);
    }
  }

  if (Cv && act == 2 && n0 >= 2 * HID_) {
    // V slice of qkv: write tile-major transposed for the attention kernel.
    const int hh = (n0 - 2 * HID_) >> 6;
    int mrow = m0 + wm + lk * 4;
    int bb = mrow >> 11, tt = mrow & (LT_ - 1);
    size_t tb = (((size_t)(bb * NHEAD_ + hh) * (LT_ / 64) + (tt >> 6)) << 12) + (tt & 63);
#pragma unroll
    for (int nf = 0; nf < 2; ++nf) {
      int d = wn + nf * 16 + lr;
      float bv = bias ? bias[n0 + d] : 0.f;
      s16x4 ov;
#pragma unroll
      for (int r = 0; r < 4; ++r) ov[r] = f2b(acc[nf][r] + bv);
      *(s16x4*)&Cv[tb + (size_t)d * 64] = ov;
    }
    return;
  }

#pragma unroll
  for (int nf = 0; nf < 2; ++nf)
#pragma unroll
    for (int r = 0; r < 4; ++r) {
      int m = mz + m0 + wm + lk * 4 + r;
      int n = n0 + wn + nf * 16 + lr;
      if (n < N) {
        float v = acc[nf][r];
        if (bias) v += bias[n];
        if (act == 1) v = 0.5f * v * (1.f + erff(v * 0.70710678118f));
        else if (act == 2 && n < HID_) v *= 0.125f;
        if (res) v += res[(size_t)m * N + n];
        if (Cf) Cf[(size_t)m * N + n] = v;
        if (Ch) Ch[(size_t)m * N + n] = f2b(v);
      }
    }
}

static inline void gemm16b(hipStream_t s, const short* A, const short* Wt, const float* bias,
                           const float* res, float* Cf, short* Ch, int M, int N, int K, int act) {
  dim3 g((N + 63) / 64, M / 64), b(512);
  ec_gemm16b<<<g, b, 0, s>>>(A, Wt, bias, res, Cf, Ch, nullptr, M, N, K, act, K, 0, 0);
}

// fixup for dsconv GEMM boundary rows (lo=0 per batch), 4-wide
__global__ __launch_bounds__(512) void ec_dsfix(
    const short* __restrict__ x16, const short* __restrict__ wt,
    const float* __restrict__ bias, float* __restrict__ dsf, short* __restrict__ ds16)
{
  const int b = blockIdx.x, o = threadIdx.x;
  float v = bias[o];
#pragma unroll
  for (int k = 1; k < 3; ++k) {
    const short* xr = x16 + ((size_t)b * LSEQ_ + (k - 1)) * HID_;
    const short* wr = wt + (size_t)o * 1536 + k * 512;
    for (int i = 0; i < 512; i += 4) {
      s16x4 xv = *(const s16x4*)(xr + i);
      s16x4 wv = *(const s16x4*)(wr + i);
      v += b2f(xv[0]) * b2f(wv[0]) + b2f(xv[1]) * b2f(wv[1])
         + b2f(xv[2]) * b2f(wv[2]) + b2f(xv[3]) * b2f(wv[3]);
    }
  }
  dsf[(size_t)b * LT_ * HID_ + o] = v;
  ds16[(size_t)b * LT_ * HID_ + o] = f2b(v);
}

// ============================================================
// Fused depthwise causal conv (DCONV=4) + SiLU, bf16 in/out
// ============================================================
__global__ __launch_bounds__(256) void ec_conv1d_silu(
    const short* __restrict__ zx16, const float* __restrict__ cwt,
    const float* __restrict__ cb, short* __restrict__ xbc16,
    short* __restrict__ B16, short* __restrict__ C16)
{
  int idx = blockIdx.x * 256 + threadIdx.x;
  const int NG = CONVD_ / 4;  // 288 channel groups
  if (idx >= BB_ * LSEQ_ * NG) return;
  int cg = idx % NG;
  int row = idx / NG;
  int l = row & (LSEQ_ - 1);
  int c0 = cg * 4;
  float4 cbv = *(const float4*)(cb + c0);
  float a0 = cbv.x, a1 = cbv.y, a2 = cbv.z, a3 = cbv.w;
#pragma unroll
  for (int j = 0; j < 4; ++j) {
    int ll = l - 3 + j;
    if (ll >= 0) {
      s16x4 xv = *(const s16x4*)(zx16 + (size_t)(row + ll - l) * DPROJ_ + DIN_ + c0);
      float4 wv = *(const float4*)(cwt + j * CONVD_ + c0);
      a0 += b2f(xv[0]) * wv.x;
      a1 += b2f(xv[1]) * wv.y;
      a2 += b2f(xv[2]) * wv.z;
      a3 += b2f(xv[3]) * wv.w;
    }
  }
  a0 = siluf(a0); a1 = siluf(a1); a2 = siluf(a2); a3 = siluf(a3);
  s16x4 pk; pk[0] = f2b(a0); pk[1] = f2b(a1); pk[2] = f2b(a2); pk[3] = f2b(a3);
  *(s16x4*)(xbc16 + (size_t)row * CONVD_ + c0) = pk;
  if (c0 >= DIN_) {
    int col = c0 - DIN_;
    if (col < 64) *(s16x4*)(B16 + (size_t)row * 64 + col) = pk;
    else          *(s16x4*)(C16 + (size_t)row * 64 + col - 64) = pk;
  }
}

// ============================================================
// SSD prep 1: per-chunk softplus(dt)+cumsum -> dts, lp, Pc
// ============================================================
__global__ __launch_bounds__(256) void ec_ssd_cumsum(
    const short* __restrict__ zx16, const float* __restrict__ dtb,
    const float* __restrict__ Alog, float* __restrict__ dts,
    float* __restrict__ lp, float* __restrict__ Pc)
{
  const int c = blockIdx.x, b = blockIdx.y, hg = blockIdx.z;
  const int t = threadIdx.x;
  const int lane = t & 63, wv = t >> 6;
  const size_t row = (size_t)b * LSEQ_ + (size_t)c * LC_ + t;
  const int h0 = hg * 8;
  __shared__ float wsum[4][8];

  bf16x8 dv = *(const bf16x8*)(zx16 + row * DPROJ_ + (DIN_ + CONVD_) + h0);
  float dt[8], cs[8];
#pragma unroll
  for (int j = 0; j < 8; ++j) {
    float x = b2f(dv[j]) + dtb[h0 + j];
    float sp = (x > 20.f) ? x : log1pf(__expf(x));
    dt[j] = sp;
    cs[j] = sp;
  }
#pragma unroll
  for (int d = 1; d < 64; d <<= 1) {
#pragma unroll
    for (int j = 0; j < 8; ++j) {
      float o = __shfl_up(cs[j], d, 64);
      if (lane >= d) cs[j] += o;
    }
  }
  if (lane == 63)
#pragma unroll
    for (int j = 0; j < 8; ++j) wsum[wv][j] = cs[j];
  __syncthreads();
#pragma unroll
  for (int j = 0; j < 8; ++j) {
    float base = 0.f;
#pragma unroll
    for (int k = 0; k < 3; ++k) if (k < wv) base += wsum[k][j];
    cs[j] += base;
  }
#pragma unroll
  for (int j = 0; j < 8; ++j) {
    int h = h0 + j;
    float lpv = -expf(Alog[h]) * cs[j];
    dts[row * NH_ + h] = dt[j];
    lp[row * NH_ + h] = lpv;
    if (t == LC_ - 1) Pc[(b * NC_ + c) * NH_ + h] = expf(lpv);
  }
}

// ============================================================
// SSD prep 3: VT[b,c,h][p][t] = bf16( dt[t,h] * x[t, h*32+p] )
// ============================================================
__global__ __launch_bounds__(64) void ec_vt(
    const short* __restrict__ xbc16, const float* __restrict__ dts, short* __restrict__ VT)
{
  const int h = blockIdx.x, c = blockIdx.y, b = blockIdx.z;
  const int l = threadIdx.x;
  const size_t rowB = (size_t)b * LSEQ_ + (size_t)c * LC_;
  const size_t vtbase = (size_t)((b * NC_ + c) * NH_ + h) * 32;
  __shared__ float tile[32][33];
  for (int tt = 0; tt < 8; ++tt) {
#pragma unroll
    for (int i = 0; i < 16; ++i) {
      int r = i * 2 + (l >> 5);
      size_t row = rowB + tt * 32 + r;
      tile[r][l & 31] = b2f(xbc16[row * CONVD_ + h * 32 + (l & 31)]) * dts[row * NH_ + h];
    }
    __syncthreads();
#pragma unroll
    for (int j = 0; j < 16; ++j) {
      int p = j * 2 + (l >> 5);
      VT[(vtbase + p) * 256 + tt * 32 + (l & 31)] = f2b(tile[l & 31][p]);
    }
    __syncthreads();
  }
}

// ============================================================
// chunk states: dedicated f32 buffer [b*NC+c][h][32*64]
// ============================================================
__device__ __forceinline__ float* state_ptr(float* stbuf, int b, int c, int h, int e)
{
  return stbuf + ((size_t)((b * NC_ + c) * NH_ + h)) * 2048 + e;
}

// ============================================================
// SSD p1 (MFMA)
// ============================================================
__global__ __launch_bounds__(64) void ec_ssd_p1(
    const short* __restrict__ B16, const short* __restrict__ VT,
    const float* __restrict__ lp, float* __restrict__ stbuf)
{
  const int h = blockIdx.x, c = blockIdx.y, b = blockIdx.z;
  const int l = threadIdx.x, lr = l & 15, lk = l >> 4;
  const size_t rowB = (size_t)b * LSEQ_ + (size_t)c * LC_;
  const size_t vtbase = (size_t)((b * NC_ + c) * NH_ + h) * 32;
  __shared__ short BT[64][264];   // B^T [n][t]
  for (int i = 0; i < 4; ++i) {
    int t = i * 64 + l;
#pragma unroll
    for (int g = 0; g < 8; ++g) {
      bf16x8 v = *(const bf16x8*)&B16[(rowB + t) * 64 + g * 8];
#pragma unroll
      for (int j = 0; j < 8; ++j) BT[g * 8 + j][t] = v[j];
    }
  }
  __syncthreads();
  const float lpE = lp[(rowB + LC_ - 1) * NH_ + h];
  f32x4 acc[2][4];
#pragma unroll
  for (int i = 0; i < 2; ++i)
#pragma unroll
    for (int j = 0; j < 4; ++j) acc[i][j] = f32x4{0.f, 0.f, 0.f, 0.f};

  for (int ks = 0; ks < 8; ++ks) {
    float wv[8];
#pragma unroll
    for (int j = 0; j < 8; ++j) {
      int t = ks * 32 + lk * 8 + j;
      wv[j] = __expf(lpE - lp[(rowB + t) * NH_ + h]);
    }
    bf16x8 af[2];
#pragma unroll
    for (int mf = 0; mf < 2; ++mf) {
      bf16x8 v = *(const bf16x8*)&VT[(vtbase + mf * 16 + lr) * 256 + ks * 32 + lk * 8];
#pragma unroll
      for (int j = 0; j < 8; ++j) af[mf][j] = f2b(b2f(v[j]) * wv[j]);
    }
#pragma unroll
    for (int nf = 0; nf < 4; ++nf) {
      bf16x8 bf = *(const bf16x8*)&BT[nf * 16 + lr][ks * 32 + lk * 8];
#pragma unroll
      for (int mf = 0; mf < 2; ++mf)
        acc[mf][nf] = __builtin_amdgcn_mfma_f32_16x16x32_bf16(af[mf], bf, acc[mf][nf], 0, 0, 0);
    }
  }
#pragma unroll
  for (int mf = 0; mf < 2; ++mf)
#pragma unroll
    for (int nf = 0; nf < 4; ++nf)
#pragma unroll
      for (int r = 0; r < 4; ++r) {
        int p = mf * 16 + lk * 4 + r, n = nf * 16 + lr;
        *state_ptr(stbuf, b, c, h, p * 64 + n) = acc[mf][nf][r];
      }
}

// ============================================================
// SSD p2: sequential prefix over chunks
// ============================================================
__global__ __launch_bounds__(512) void ec_scan_p2(
    float* __restrict__ stbuf, const float* __restrict__ Pc)
{
  const int h = blockIdx.x, b = blockIdx.y;
  const int tid = threadIdx.x;
  const int e = (tid >> 4) * 64 + (tid & 15) * 4;
  float h0 = 0.f, h1 = 0.f, h2 = 0.f, h3 = 0.f;
  for (int c = 0; c < NC_; ++c) {
    float* ptr = state_ptr(stbuf, b, c, h, e);
    float4 S = *(float4*)ptr;
    *(float4*)ptr = make_float4(h0, h1, h2, h3);
    float P = Pc[(b * NC_ + c) * NH_ + h];
    h0 = h0 * P + S.x;
    h1 = h1 * P + S.y;
    h2 = h2 * P + S.z;
    h3 = h3 * P + S.w;
  }
}

// ============================================================
// SSD p3 (MFMA, flash-like)
// ============================================================
__global__ __launch_bounds__(256) void ec_ssd_p3(
    const short* __restrict__ B16, const short* __restrict__ C16,
    const short* __restrict__ VT, const float* __restrict__ lp,
    const short* __restrict__ xbc16, const float* __restrict__ Dp,
    float* __restrict__ stbuf, short* __restrict__ y16)
{
  const int h = blockIdx.x, c = blockIdx.y, b = blockIdx.z;
  const int tid = threadIdx.x;
  const int w = tid >> 6, l = tid & 63, lr = l & 15, lk = l >> 4;
  const size_t rowB = (size_t)b * LSEQ_ + (size_t)c * LC_;
  const size_t vtbase = (size_t)((b * NC_ + c) * NH_ + h) * 32;
  __shared__ short hI[32][72];
  __shared__ short Pl[4][64][72];

  for (int i = tid; i < 2048; i += 256)
    hI[i >> 6][i & 63] = f2b(*state_ptr(stbuf, b, c, h, i));
  __syncthreads();

  const int t0 = w * 64;
  bf16x8 cf[4][2];
#pragma unroll
  for (int tf = 0; tf < 4; ++tf)
#pragma unroll
    for (int ks = 0; ks < 2; ++ks)
      cf[tf][ks] = *(const bf16x8*)&C16[(rowB + t0 + tf * 16 + lr) * 64 + ks * 32 + lk * 8];

  // Y1 = C @ hInit^T
  f32x4 Y[4][2];
#pragma unroll
  for (int i = 0; i < 4; ++i)
#pragma unroll
    for (int j = 0; j < 2; ++j) Y[i][j] = f32x4{0.f, 0.f, 0.f, 0.f};
#pragma unroll
  for (int nf = 0; nf < 2; ++nf)
#pragma unroll
    for (int ks = 0; ks < 2; ++ks) {
      bf16x8 hf = *(const bf16x8*)&hI[nf * 16 + lr][ks * 32 + lk * 8];
#pragma unroll
      for (int mf = 0; mf < 4; ++mf)
        Y[mf][nf] = __builtin_amdgcn_mfma_f32_16x16x32_bf16(cf[mf][ks], hf, Y[mf][nf], 0, 0, 0);
    }
#pragma unroll
  for (int mf = 0; mf < 4; ++mf)
#pragma unroll
    for (int r = 0; r < 4; ++r) {
      float e = __expf(lp[(rowB + t0 + mf * 16 + lk * 4 + r) * NH_ + h]);
      Y[mf][0][r] *= e;
      Y[mf][1][r] *= e;
    }
  float tlp[4];
#pragma unroll
  for (int tf = 0; tf < 4; ++tf)
    tlp[tf] = lp[(rowB + t0 + tf * 16 + lr) * NH_ + h];

  for (int st = 0; st <= w; ++st) {
    const int s0 = st * 64;
#pragma unroll
    for (int half = 0; half < 2; ++half) {
      f32x4 ST[2][4];
#pragma unroll
      for (int i = 0; i < 2; ++i)
#pragma unroll
        for (int j = 0; j < 4; ++j) ST[i][j] = f32x4{0.f, 0.f, 0.f, 0.f};
#pragma unroll
      for (int sf2 = 0; sf2 < 2; ++sf2) {
        int sf = half * 2 + sf2;
#pragma unroll
        for (int ks = 0; ks < 2; ++ks) {
          bf16x8 bfr = *(const bf16x8*)&B16[(rowB + s0 + sf * 16 + lr) * 64 + ks * 32 + lk * 8];
#pragma unroll
          for (int tf = 0; tf < 4; ++tf)
            ST[sf2][tf] = __builtin_amdgcn_mfma_f32_16x16x32_bf16(bfr, cf[tf][ks], ST[sf2][tf], 0, 0, 0);
        }
      }
#pragma unroll
      for (int sf2 = 0; sf2 < 2; ++sf2) {
        int sf = half * 2 + sf2;
        float slp[4];
#pragma unroll
        for (int r = 0; r < 4; ++r)
          slp[r] = lp[(rowB + s0 + sf * 16 + lk * 4 + r) * NH_ + h];
#pragma unroll
        for (int tf = 0; tf < 4; ++tf) {
          float pv[4];
#pragma unroll
          for (int r = 0; r < 4; ++r) {
            pv[r] = ST[sf2][tf][r] * __expf(tlp[tf] - slp[r]);
            if (st == w && (sf * 16 + lk * 4 + r) > (tf * 16 + lr)) pv[r] = 0.f;
          }
          union { float f; unsigned u; } q0, q1, q2, q3;
          q0.f = pv[0]; q1.f = pv[1]; q2.f = pv[2]; q3.f = pv[3];
          uint2 pk;
          pk.x = (q0.u >> 16) | (q1.u & 0xffff0000u);
          pk.y = (q2.u >> 16) | (q3.u & 0xffff0000u);
          *(uint2*)&Pl[w][tf * 16 + lr][sf * 16 + lk * 4] = pk;
        }
      }
    }
    // wave-private LDS write->read fence (rule #18)
    __builtin_amdgcn_sched_barrier(0);
    asm volatile("s_waitcnt lgkmcnt(0)" ::: "memory");
    __builtin_amdgcn_sched_barrier(0);
#pragma unroll
    for (int ks = 0; ks < 2; ++ks) {
      bf16x8 vf[2];
#pragma unroll
      for (int nf = 0; nf < 2; ++nf)
        vf[nf] = *(const bf16x8*)&VT[(vtbase + nf * 16 + lr) * 256 + s0 + ks * 32 + lk * 8];
#pragma unroll
      for (int mf = 0; mf < 4; ++mf) {
        bf16x8 pf = *(const bf16x8*)&Pl[w][mf * 16 + lr][ks * 32 + lk * 8];
#pragma unroll
        for (int nf = 0; nf < 2; ++nf)
          Y[mf][nf] = __builtin_amdgcn_mfma_f32_16x16x32_bf16(pf, vf[nf], Y[mf][nf], 0, 0, 0);
      }
    }
  }
  // epilogue with D*x
  const float Dh = Dp[h];
#pragma unroll
  for (int mf = 0; mf < 4; ++mf)
#pragma unroll
    for (int r = 0; r < 4; ++r) {
      size_t yrow = rowB + t0 + mf * 16 + lk * 4 + r;
#pragma unroll
      for (int nf = 0; nf < 2; ++nf) {
        float xv = b2f(xbc16[yrow * CONVD_ + h * 32 + nf * 16 + lr]);
        y16[yrow * DIN_ + h * 32 + nf * 16 + lr] = f2b(Y[mf][nf][r] + Dh * xv);
      }
    }
}

// ============================================================
// t = y * silu(z); out = rmsnorm(t)*nw -> bf16 (row width 1024)
// ============================================================
__global__ __launch_bounds__(256) void ec_gate_rms16(
    const short* __restrict__ y16, const short* __restrict__ zx16,
    const float* __restrict__ nw, short* __restrict__ out)
{
  const int row = blockIdx.x;
  const int c0 = threadIdx.x * 4;
  s16x4 yv = *(const s16x4*)(y16 + (size_t)row * DIN_ + c0);
  s16x4 zv = *(const s16x4*)(zx16 + (size_t)row * DPROJ_ + c0);
  float v[4]; float ss = 0.f;
#pragma unroll
  for (int j = 0; j < 4; ++j) {
    float t = b2f(yv[j]) * siluf(b2f(zv[j]));
    v[j] = t; ss += t * t;
  }
#pragma unroll
  for (int m = 32; m >= 1; m >>= 1) ss += __shfl_xor(ss, m, 64);
  __shared__ float buf[4];
  if ((threadIdx.x & 63) == 0) buf[threadIdx.x >> 6] = ss;
  __syncthreads();
  ss = buf[0] + buf[1] + buf[2] + buf[3];
  float scale = rsqrtf(ss / (float)DIN_ + 1e-5f);
  float4 wv = *(const float4*)(nw + c0);
  s16x4 ov;
  ov[0] = f2b(v[0] * scale * wv.x);
  ov[1] = f2b(v[1] * scale * wv.y);
  ov[2] = f2b(v[2] * scale * wv.z);
  ov[3] = f2b(v[3] * scale * wv.w);
  *(s16x4*)(out + (size_t)row * DIN_ + c0) = ov;
}

// ============================================================
// out = rmsnorm(a16 + b)*w -> fp32 + bf16 (row width 512, a is bf16)
// ============================================================
__global__ __launch_bounds__(128) void ec_rmsadd16(
    const short* __restrict__ a16, const float* __restrict__ bres,
    const float* __restrict__ w, float* __restrict__ out, short* __restrict__ out16)
{
  const int row = blockIdx.x;
  const int c0 = threadIdx.x * 4;
  s16x4 av = *(const s16x4*)(a16 + (size_t)row * HID_ + c0);
  float4 brv = *(const float4*)(bres + (size_t)row * HID_ + c0);
  float v[4]; float ss = 0.f;
  v[0] = b2f(av[0]) + brv.x; v[1] = b2f(av[1]) + brv.y;
  v[2] = b2f(av[2]) + brv.z; v[3] = b2f(av[3]) + brv.w;
#pragma unroll
  for (int j = 0; j < 4; ++j) ss += v[j] * v[j];
#pragma unroll
  for (int m = 32; m >= 1; m >>= 1) ss += __shfl_xor(ss, m, 64);
  __shared__ float buf[2];
  if ((threadIdx.x & 63) == 0) buf[threadIdx.x >> 6] = ss;
  __syncthreads();
  ss = buf[0] + buf[1];
  float scale = rsqrtf(ss / (float)HID_ + 1e-5f);
  float4 wv = *(const float4*)(w + c0);
  float o0 = v[0] * scale * wv.x, o1 = v[1] * scale * wv.y;
  float o2 = v[2] * scale * wv.z, o3 = v[3] * scale * wv.w;
  *(float4*)(out + (size_t)row * HID_ + c0) = make_float4(o0, o1, o2, o3);
  s16x4 ov; ov[0] = f2b(o0); ov[1] = f2b(o1); ov[2] = f2b(o2); ov[3] = f2b(o3);
  *(s16x4*)(out16 + (size_t)row * HID_ + c0) = ov;
}

// ============================================================
// layernorm(in)*w + b -> fp32 (+ optional bf16) (row width 512)
// ============================================================
__global__ __launch_bounds__(128) void ec_ln16(
    const float* __restrict__ in, const float* __restrict__ w,
    const float* __restrict__ bb, float* __restrict__ out, short* __restrict__ out16)
{
  const int row = blockIdx.x;
  const float* ir = in + (size_t)row * HID_;
  float v[4]; float s = 0.f, s2 = 0.f;
#pragma unroll
  for (int j = 0; j < 4; ++j) {
    int c = j * 128 + threadIdx.x;
    float t = ir[c];
    v[j] = t; s += t; s2 += t * t;
  }
#pragma unroll
  for (int m = 32; m >= 1; m >>= 1) { s += __shfl_xor(s, m, 64); s2 += __shfl_xor(s2, m, 64); }
  __shared__ float buf[4];
  if ((threadIdx.x & 63) == 0) { int wi = threadIdx.x >> 6; buf[wi * 2] = s; buf[wi * 2 + 1] = s2; }
  __syncthreads();
  s = buf[0] + buf[2]; s2 = buf[1] + buf[3];
  float mean = s / (float)HID_;
  float var = s2 / (float)HID_ - mean * mean;
  float inv = rsqrtf(var + 1e-5f);
#pragma unroll
  for (int j = 0; j < 4; ++j) {
    int c = j * 128 + threadIdx.x;
    float o = (v[j] - mean) * inv * w[c] + bb[c];
    out[(size_t)row * HID_ + c] = o;
    if (out16) out16[(size_t)row * HID_ + c] = f2b(o);
  }
}

// ============================================================
// fused double layernorm: out = LN2(LN1(in)) (row width 512)
// ============================================================
__global__ __launch_bounds__(128) void ec_ln2x(
    const float* __restrict__ in, const float* __restrict__ w1,
    const float* __restrict__ bb1, const float* __restrict__ w2,
    const float* __restrict__ bb2, float* __restrict__ out)
{
  const int row = blockIdx.x;
  const float* ir = in + (size_t)row * HID_;
  float v[4]; float s = 0.f, s2 = 0.f;
#pragma unroll
  for (int j = 0; j < 4; ++j) {
    int c = j * 128 + threadIdx.x;
    float t = ir[c];
    v[j] = t; s += t; s2 += t * t;
  }
#pragma unroll
  for (int m = 32; m >= 1; m >>= 1) { s += __shfl_xor(s, m, 64); s2 += __shfl_xor(s2, m, 64); }
  __shared__ float buf[4];
  if ((threadIdx.x & 63) == 0) { int wi = threadIdx.x >> 6; buf[wi * 2] = s; buf[wi * 2 + 1] = s2; }
  __syncthreads();
  s = buf[0] + buf[2]; s2 = buf[1] + buf[3];
  float mean = s / (float)HID_;
  float var = s2 / (float)HID_ - mean * mean;
  float inv = rsqrtf(var + 1e-5f);
  float o[4]; float t1 = 0.f, t2 = 0.f;
#pragma unroll
  for (int j = 0; j < 4; ++j) {
    int c = j * 128 + threadIdx.x;
    float t = (v[j] - mean) * inv * w1[c] + bb1[c];
    o[j] = t; t1 += t; t2 += t * t;
  }
#pragma unroll
  for (int m = 32; m >= 1; m >>= 1) { t1 += __shfl_xor(t1, m, 64); t2 += __shfl_xor(t2, m, 64); }
  __syncthreads();
  if ((threadIdx.x & 63) == 0) { int wi = threadIdx.x >> 6; buf[wi * 2] = t1; buf[wi * 2 + 1] = t2; }
  __syncthreads();
  t1 = buf[0] + buf[2]; t2 = buf[1] + buf[3];
  float mean2 = t1 / (float)HID_;
  float var2 = t2 / (float)HID_ - mean2 * mean2;
  float inv2 = rsqrtf(var2 + 1e-5f);
#pragma unroll
  for (int j = 0; j < 4; ++j) {
    int c = j * 128 + threadIdx.x;
    out[(size_t)row * HID_ + c] = (o[j] - mean2) * inv2 * w2[c] + bb2[c];
  }
}

// ============================================================
// MFMA flash attention, 128-row Q tile, 8 waves, KV-split (NS_=8),
// defer-max, bf16 partials, tile-major V^T input, DOUBLE-BUFFERED K/V
// (one barrier per K-tile: stage t+1 into buf^1 while computing buf).
// grid (LT_/128, NHEAD_, BB_*NS_), 512 threads.
// ============================================================
__global__ __launch_bounds__(512) void ec_attn16(
    const short* __restrict__ qkv, const short* __restrict__ vt16,
    short* __restrict__ Op, float2* __restrict__ ml)
{
  const int b = blockIdx.z & 1, split = blockIdx.z >> 1;
  const int h = blockIdx.y, qt = blockIdx.x;
  __shared__ short Kl[2][64 * 68];
  __shared__ short Vl[2][64 * 68];
  __shared__ short Pl[128 * 68];
  const int tid = threadIdx.x;
  const int l = tid & 63, w = tid >> 6;   // 8 waves, wave w owns q rows w*16..+16
  const int lr = l & 15, lk = l >> 4;

  const size_t qrow = (size_t)b * LT_ + qt * 128 + w * 16 + lr;
  bf16x8 qf[2];
  qf[0] = *(const bf16x8*)&qkv[qrow * 1536 + h * HD_ + lk * 8];
  qf[1] = *(const bf16x8*)&qkv[qrow * 1536 + h * HD_ + lk * 8 + 32];

  float mrun[4] = {-1e30f, -1e30f, -1e30f, -1e30f};
  float lsum[4] = {0.f, 0.f, 0.f, 0.f};
  f32x4 O[4];
#pragma unroll
  for (int df = 0; df < 4; ++df) O[df] = f32x4{0.f, 0.f, 0.f, 0.f};

  const int krow = tid >> 3, kcg = (tid & 7) * 8;   // K: 512 thr x 16B = 8KB tile
  const short* vtile = vt16 + (size_t)(b * NHEAD_ + h) * (LT_ / 64) * 4096;
  const int vofs = tid * 8;
  const int vlds = (tid >> 3) * 68 + (tid & 7) * 8;

  auto stageKV = [&](int kt, int bufi) {
    const size_t krbase = (size_t)b * LT_ + kt * 64;
    const short* kp = &qkv[(krbase + krow) * 1536 + HID_ + h * HD_ + kcg];
    *(bf16x8*)&Kl[bufi][krow * 68 + kcg] = *(const bf16x8*)kp;
    bf16x8 vv = *(const bf16x8*)&vtile[(size_t)kt * 4096 + vofs];
    *(bf16x8*)&Vl[bufi][vlds] = vv;
  };

  stageKV(split * KTS_, 0);
  __syncthreads();

  for (int i = 0; i < KTS_; ++i) {
    const int cur = i & 1;
    if (i + 1 < KTS_) stageKV(split * KTS_ + i + 1, cur ^ 1);

    f32x4 S[4];
#pragma unroll
    for (int nf = 0; nf < 4; ++nf) S[nf] = f32x4{0.f, 0.f, 0.f, 0.f};
#pragma unroll
    for (int ks = 0; ks < 2; ++ks)
#pragma unroll
      for (int nf = 0; nf < 4; ++nf) {
        bf16x8 kb = *(const bf16x8*)&Kl[cur][(nf * 16 + lr) * 68 + ks * 32 + lk * 8];
        S[nf] = __builtin_amdgcn_mfma_f32_16x16x32_bf16(qf[ks], kb, S[nf], 0, 0, 0);
      }

    // defer-max: scores already scaled; skip rescale unless growth > 8
    int ok = 1;
#pragma unroll
    for (int nf = 0; nf < 4; ++nf)
#pragma unroll
      for (int r = 0; r < 4; ++r)
        ok &= (S[nf][r] <= mrun[r] + 8.f);
    if (!__all(ok)) {
      float fr[4];
#pragma unroll
      for (int r = 0; r < 4; ++r) {
        float mt = fmaxf(fmaxf(S[0][r], S[1][r]), fmaxf(S[2][r], S[3][r]));
        mt = fmaxf(mt, __shfl_xor(mt, 1));
        mt = fmaxf(mt, __shfl_xor(mt, 2));
        mt = fmaxf(mt, __shfl_xor(mt, 4));
        mt = fmaxf(mt, __shfl_xor(mt, 8));
        float mn = fmaxf(mrun[r], mt);
        fr[r] = __expf(mrun[r] - mn);
        mrun[r] = mn;
        lsum[r] *= fr[r];
      }
#pragma unroll
      for (int df = 0; df < 4; ++df) {
        O[df][0] *= fr[0]; O[df][1] *= fr[1]; O[df][2] *= fr[2]; O[df][3] *= fr[3];
      }
    }
#pragma unroll
    for (int nf = 0; nf < 4; ++nf)
#pragma unroll
      for (int r = 0; r < 4; ++r) {
        float p = __expf(S[nf][r] - mrun[r]);
        lsum[r] += p;
        Pl[(w * 16 + lk * 4 + r) * 68 + nf * 16 + lr] = f2bt(p);
      }

#pragma unroll
    for (int ks = 0; ks < 2; ++ks) {
      bf16x8 pa = *(const bf16x8*)&Pl[(w * 16 + lr) * 68 + ks * 32 + lk * 8];
#pragma unroll
      for (int df = 0; df < 4; ++df) {
        bf16x8 vb = *(const bf16x8*)&Vl[cur][(df * 16 + lr) * 68 + ks * 32 + lk * 8];
        O[df] = __builtin_amdgcn_mfma_f32_16x16x32_bf16(pa, vb, O[df], 0, 0, 0);
      }
    }
    __syncthreads();
  }

#pragma unroll
  for (int r = 0; r < 4; ++r) {
    lsum[r] += __shfl_xor(lsum[r], 1);
    lsum[r] += __shfl_xor(lsum[r], 2);
    lsum[r] += __shfl_xor(lsum[r], 4);
    lsum[r] += __shfl_xor(lsum[r], 8);
  }
  const size_t sstride = (size_t)BB_ * NHEAD_ * LT_;
  const size_t obase = (size_t)split * sstride + ((size_t)b * NHEAD_ + h) * LT_ + qt * 128 + w * 16;
#pragma unroll
  for (int df = 0; df < 4; ++df)
#pragma unroll
    for (int r = 0; r < 4; ++r)
      Op[(obase + lk * 4 + r) * 64 + df * 16 + lr] = f2b(O[df][r]);
  if (lr == 0)
#pragma unroll
    for (int r = 0; r < 4; ++r)
      ml[obase + lk * 4 + r] = make_float2(mrun[r], lsum[r]);
}

// ============================================================
// attention split-combine (bf16 partials)
// ============================================================
__global__ __launch_bounds__(256) void ec_attn_comb(
    const short* __restrict__ Op, const float2* __restrict__ ml, short* __restrict__ out)
{
  const int qt = blockIdx.x, h = blockIdx.y, b = blockIdx.z;
  const int r = threadIdx.x >> 2, c0 = (threadIdx.x & 3) * 16;
  const int qrow = qt * 64 + r;
  const size_t sstride = (size_t)BB_ * NHEAD_ * LT_;
  const size_t rb = ((size_t)b * NHEAD_ + h) * LT_ + qrow;
  float m[NS_], lv[NS_];
  float mmax = -1e30f;
#pragma unroll
  for (int s = 0; s < NS_; ++s) {
    float2 v = ml[rb + s * sstride];
    m[s] = v.x; lv[s] = v.y;
    mmax = fmaxf(mmax, m[s]);
  }
  float den = 0.f, wsc[NS_];
#pragma unroll
  for (int s = 0; s < NS_; ++s) { wsc[s] = __expf(m[s] - mmax); den += lv[s] * wsc[s]; }
  float inv = 1.f / den;
  float o[16];
#pragma unroll
  for (int i = 0; i < 16; ++i) o[i] = 0.f;
#pragma unroll
  for (int s = 0; s < NS_; ++s) {
    const short* p = Op + (rb + s * sstride) * 64 + c0;
    float wq = wsc[s];
#pragma unroll
    for (int i = 0; i < 4; ++i) {
      s16x4 v = *(const s16x4*)(p + i * 4);
      o[i * 4 + 0] += b2f(v[0]) * wq; o[i * 4 + 1] += b2f(v[1]) * wq;
      o[i * 4 + 2] += b2f(v[2]) * wq; o[i * 4 + 3] += b2f(v[3]) * wq;
    }
  }
  short* op = out + ((size_t)b * LT_ + qrow) * HID_ + h * HD_ + c0;
#pragma unroll
  for (int i = 0; i < 16; ++i) op[i] = f2b(o[i] * inv);
}

// ============================================================
// host launch
// ============================================================
extern "C" void kernel_launch(void* const* d_in, const int* in_sizes, int n_in,
                              void* d_out, int out_size, void* d_ws, size_t ws_size,
                              hipStream_t stream)
{
  const float* x_in   = (const float*)d_in[0];
  const float* Wp     = (const float*)d_in[1];
  const float* bp     = (const float*)d_in[2];
  const float* m_Wi[2]   = {(const float*)d_in[3],  (const float*)d_in[11]};
  const float* m_cw[2]   = {(const float*)d_in[4],  (const float*)d_in[12]};
  const float* m_cb[2]   = {(const float*)d_in[5],  (const float*)d_in[13]};
  const float* m_dtb[2]  = {(const float*)d_in[6],  (const float*)d_in[14]};
  const float* m_Alog[2] = {(const float*)d_in[7],  (const float*)d_in[15]};
  const float* m_D[2]    = {(const float*)d_in[8],  (const float*)d_in[16]};
  const float* m_nw[2]   = {(const float*)d_in[9],  (const float*)d_in[17]};
  const float* m_Wo[2]   = {(const float*)d_in[10], (const float*)d_in[18]};
  const float* n_w[2]    = {(const float*)d_in[19], (const float*)d_in[20]};
  const float* ds_w   = (const float*)d_in[21];
  const float* ds_b   = (const float*)d_in[22];
  const float* t_Wqkv = (const float*)d_in[23];
  const float* t_bqkv = (const float*)d_in[24];
  const float* t_Wo   = (const float*)d_in[25];
  const float* t_bo   = (const float*)d_in[26];
  const float* t_W1   = (const float*)d_in[27];
  const float* t_b1   = (const float*)d_in[28];
  const float* t_W2   = (const float*)d_in[29];
  const float* t_b2   = (const float*)d_in[30];
  const float* t_ln1w = (const float*)d_in[31];
  const float* t_ln1b = (const float*)d_in[32];
  const float* t_ln2w = (const float*)d_in[33];
  const float* t_ln2b = (const float*)d_in[34];
  const float* on_w   = (const float*)d_in[35];
  const float* on_b   = (const float*)d_in[36];

  char* ws = (char*)d_ws;
  float* bx    = (float*)(ws + 0);                    // [8192,512] f32 residual
  short* zx16  = (short*)(ws + 16777216);             // [8192,2208] bf16 zxbcdt
  float* stbuf = (float*)(ws + 16777216 + 36175872);  // [1024][2048] f32 chunk states
  short* xbc16 = (short*)(ws + 89128960);             // [8192,1152] bf16 xBC
  short* y16   = (short*)(ws + 126877696);            // [8192,1024] bf16 scan y
  short* VT    = (short*)(ws + 143654912);            // [b,c,h][32][256] bf16 dtx^T
  float* lp    = (float*)(ws + 160432128);            // [8192,32] log-decay prefix
  float* dts   = (float*)(ws + 161480704);            // [8192,32] dt
  short* wslot = (short*)(ws + 162529280);            // bf16 weight slot / B16+C16
  float* Pc    = (float*)(ws + 165150720);            // 4 KB
  float* cwt   = (float*)(ws + 165154816);            // [4][1152] f32 transposed conv w

  short* B16 = wslot;                          // [8192,64] bf16 (scan window only)
  short* C16 = wslot + 524288;                 // [8192,64]
  short* a16buf = (short*)(ws + 126877696);    // out-proj bf16 out (over dead y16)

  short* x16     = (short*)(ws + 126877696);   // input bf16 (dead before p3)
  short* bx16    = (short*)(ws + 89128960);    // residual bf16 (time-mux with xbc16)
  short* gated16 = (short*)(ws + 89128960 + 18874368);

  short*  Opart = (short*)(ws + 89128960);                 // NS*B*H*LT*64 bf16 = 33.5 MB
  float2* mlbuf = (float2*)(ws + 89128960 + 33554432);     // 2 MB

  char* tzone = ws + 16777216;
  short* ds16  = (short*)tzone;
  float* dsf   = (float*)(tzone + 4194304);
  short* qkv16 = (short*)(tzone + 12582912);
  short* att16 = (short*)(tzone + 25165824);
  float* bt1   = (float*)(tzone + 29360128);
  short* ln116 = (short*)(tzone + 37748736);
  float* bxt2  = (float*)(tzone + 41943040);
  short* ff16  = (short*)(tzone + 50331648);
  float* bt2   = (float*)(tzone + 58720256);
  short* vt16  = (short*)(tzone + 67108864);   // [B,H,kt][d*64+key] bf16 V^T (4 MB)

  const int MR = BB_ * LSEQ_;  // 8192
  const int MT = BB_ * LT_;    // 4096

  // input projection; writes f32 residual + bf16 copy
  ec_f2b<<<(MR * 1024 / 8 + 255) / 256, 256, 0, stream>>>(x_in, x16, MR * 1024 / 8);
  ec_w2bt<<<dim3(1024 / 32, 512 / 32), 256, 0, stream>>>(Wp, wslot, 1024, 512);
  gemm16b(stream, x16, wslot, bp, nullptr, bx, bx16, MR, HID_, 1024, 0);

  for (int blk = 0; blk < 2; ++blk) {
    ec_w2bt<<<dim3(512 / 32, 2208 / 32), 256, 0, stream>>>(m_Wi[blk], wslot, 512, 2208);
    gemm16b(stream, bx16, wslot, nullptr, nullptr, nullptr, zx16, MR, DPROJ_, HID_, 0);
    ec_cwt<<<(CONVD_ * 4 + 255) / 256, 256, 0, stream>>>(m_cw[blk], cwt);
    ec_conv1d_silu<<<(MR * (CONVD_ / 4) + 255) / 256, 256, 0, stream>>>(
        zx16, cwt, m_cb[blk], xbc16, B16, C16);
    ec_ssd_cumsum<<<dim3(NC_, BB_, NH_ / 8), 256, 0, stream>>>(zx16, m_dtb[blk], m_Alog[blk], dts, lp, Pc);
    ec_vt<<<dim3(NH_, NC_, BB_), 64, 0, stream>>>(xbc16, dts, VT);
    ec_ssd_p1<<<dim3(NH_, NC_, BB_), 64, 0, stream>>>(B16, VT, lp, stbuf);
    ec_scan_p2<<<dim3(NH_, BB_), 512, 0, stream>>>(stbuf, Pc);
    ec_ssd_p3<<<dim3(NH_, NC_, BB_), 256, 0, stream>>>(B16, C16, VT, lp, xbc16, m_D[blk], stbuf, y16);
    ec_gate_rms16<<<MR, 256, 0, stream>>>(y16, zx16, m_nw[blk], gated16);
    ec_w2bt<<<dim3(1024 / 32, 512 / 32), 256, 0, stream>>>(m_Wo[blk], wslot, 1024, 512);
    gemm16b(stream, gated16, wslot, nullptr, nullptr, nullptr, a16buf, MR, HID_, DIN_, 0);
    ec_rmsadd16<<<MR, 128, 0, stream>>>(a16buf, bx, n_w[blk], bx, bx16);
  }

  // downsample conv as implicit-im2col GEMM
  ec_dswt<<<(HID_ * 1536 + 255) / 256, 256, 0, stream>>>(ds_w, wslot);
  {
    dim3 g(512 / 64, LT_ / 64, BB_), b(512);
    ec_gemm16b<<<g, b, 0, stream>>>(bx16 - 512, wslot, ds_b, nullptr, dsf, ds16, nullptr,
                                    LT_, HID_, 1536, 0, 1024, (long)LSEQ_ * HID_, LT_);
  }
  ec_dsfix<<<BB_, 512, 0, stream>>>(bx16, wslot, ds_b, dsf, ds16);

  // transformer layer; qkv GEMM pre-scales q cols by 0.125 (act=2) and
  // writes the V slice tile-major transposed into vt16 (Cv path).
  ec_w2bt<<<dim3(512 / 32, 1536 / 32), 256, 0, stream>>>(t_Wqkv, wslot, 512, 1536);
  {
    dim3 g(1536 / 64, MT / 64), b(512);
    ec_gemm16b<<<g, b, 0, stream>>>(ds16, wslot, t_bqkv, nullptr, nullptr, qkv16, vt16,
                                    MT, 3 * HID_, HID_, 2, HID_, 0, 0);
  }
  ec_attn16<<<dim3(LT_ / 128, NHEAD_, BB_ * NS_), 512, 0, stream>>>(qkv16, vt16, Opart, mlbuf);
  ec_attn_comb<<<dim3(LT_ / 64, NHEAD_, BB_), 256, 0, stream>>>(Opart, mlbuf, att16);
  ec_w2bt<<<dim3(512 / 32, 512 / 32), 256, 0, stream>>>(t_Wo, wslot, 512, 512);
  gemm16b(stream, att16, wslot, t_bo, dsf, bt1, nullptr, MT, HID_, HID_, 0);
  ec_ln16<<<MT, 128, 0, stream>>>(bt1, t_ln1w, t_ln1b, bxt2, ln116);
  ec_w2bt<<<dim3(512 / 32, 1024 / 32), 256, 0, stream>>>(t_W1, wslot, 512, 1024);
  gemm16b(stream, ln116, wslot, t_b1, nullptr, nullptr, ff16, MT, DFF_, HID_, 1);
  ec_w2bt<<<dim3(1024 / 32, 512 / 32), 256, 0, stream>>>(t_W2, wslot, 1024, 512);
  gemm16b(stream, ff16, wslot, t_b2, bxt2, bt2, nullptr, MT, HID_, DFF_, 0);
  ec_ln2x<<<MT, 128, 0, stream>>>(bt2, t_ln2w, t_ln2b, on_w, on_b, (float*)d_out);
}